// Round 5
// baseline (693.901 us; speedup 1.0000x reference)
//
#include <hip/hip_runtime.h>
#include <cstddef>
#include <cstdint>

#define LRELU_ALPHA 0.2f
#define BIN_SHIFT 9
#define BIN_ROWS  (1 << BIN_SHIFT)   // 512 rows per bucket
// packed pair: (local_row << 17) | dst  -- requires N <= 131072 (N = 100000)
#define DST_BITS 17
#define DST_MASK ((1 << DST_BITS) - 1)

typedef _Float16 f16x8 __attribute__((ext_vector_type(8)));
typedef _Float16 f16x4 __attribute__((ext_vector_type(4)));
typedef _Float16 f16x2 __attribute__((ext_vector_type(2)));
typedef float    f32x4 __attribute__((ext_vector_type(4)));

// ---------------------------------------------------------------------------
// CSR build, locality-bucketed, packed pairs
// ---------------------------------------------------------------------------
__global__ __launch_bounds__(256) void bucket_count_kernel(const int* __restrict__ src,
                                                           int* __restrict__ bhist, int E)
{
    __shared__ int hist[256];
    int t = threadIdx.x;
    hist[t] = 0;
    __syncthreads();
    int base = blockIdx.x * 4096;
#pragma unroll
    for (int j = 0; j < 16; ++j) {
        int i = base + j * 256 + t;
        if (i < E) atomicAdd(&hist[src[i] >> BIN_SHIFT], 1);
    }
    __syncthreads();
    if (hist[t]) atomicAdd(&bhist[t], hist[t]);
}

__global__ __launch_bounds__(256) void bucket_scan_kernel(const int* __restrict__ bhist,
                                                          int* __restrict__ bbase,
                                                          int* __restrict__ gcur, int E)
{
    __shared__ int buf[256];
    int t = threadIdx.x;
    int v = bhist[t];
    buf[t] = v;
    __syncthreads();
    for (int off = 1; off < 256; off <<= 1) {
        int u = (t >= off) ? buf[t - off] : 0;
        __syncthreads();
        buf[t] += u;
        __syncthreads();
    }
    int excl = buf[t] - v;
    bbase[t] = excl;
    gcur[t] = excl;
    if (t == 255) bbase[256] = buf[255];
}

// bin packed (lrow|dst) into bucket-contiguous order
__global__ __launch_bounds__(256) void pass1_bin_kernel(const int* __restrict__ src,
                                                        const int* __restrict__ dst,
                                                        int* __restrict__ gcur,
                                                        int* __restrict__ pairs, int E)
{
    __shared__ int hist[256];
    __shared__ int cur[256];
    int t = threadIdx.x;
    hist[t] = 0;
    __syncthreads();
    int base = blockIdx.x * 4096;
    int s_[16], d_[16];
#pragma unroll
    for (int j = 0; j < 16; ++j) {
        int i = base + j * 256 + t;
        if (i < E) {
            s_[j] = src[i];
            d_[j] = dst[i];
            atomicAdd(&hist[s_[j] >> BIN_SHIFT], 1);
        } else s_[j] = -1;
    }
    __syncthreads();
    cur[t] = atomicAdd(&gcur[t], hist[t]);
    __syncthreads();
#pragma unroll
    for (int j = 0; j < 16; ++j) {
        if (s_[j] >= 0) {
            int pos = atomicAdd(&cur[s_[j] >> BIN_SHIFT], 1);
            pairs[pos] = ((s_[j] & (BIN_ROWS - 1)) << DST_BITS) | d_[j];
        }
    }
}

__global__ __launch_bounds__(256) void row_count_kernel(const int* __restrict__ pairs,
                                                        const int* __restrict__ bbase,
                                                        int* __restrict__ cnt, int N)
{
    __shared__ int c[BIN_ROWS];
    int b = blockIdx.x, t = threadIdx.x;
    int rowbase = b << BIN_SHIFT;
    int nrows = min(BIN_ROWS, N - rowbase);
    c[t] = 0; c[t + 256] = 0;
    __syncthreads();
    int beg = bbase[b], end = bbase[b + 1];
    for (int i = beg + t; i < end; i += 256)
        atomicAdd(&c[pairs[i] >> DST_BITS], 1);
    __syncthreads();
    if (t < nrows) cnt[rowbase + t] = c[t];
    if (t + 256 < nrows) cnt[rowbase + t + 256] = c[t + 256];
}

__global__ __launch_bounds__(256) void bsum_kernel(const int* __restrict__ cnt,
                                                   int* __restrict__ bsum, int n)
{
    __shared__ int red[4];
    int b = blockIdx.x, t = threadIdx.x;
    int base = b * 1024;
    int s = 0;
#pragma unroll
    for (int j = 0; j < 4; ++j) {
        int i = base + j * 256 + t;
        s += (i < n) ? cnt[i] : 0;
    }
#pragma unroll
    for (int off = 32; off; off >>= 1) s += __shfl_xor(s, off);
    if ((t & 63) == 0) red[t >> 6] = s;
    __syncthreads();
    if (t == 0) bsum[b] = red[0] + red[1] + red[2] + red[3];
}

__global__ __launch_bounds__(128) void bscan_kernel(int* __restrict__ bsum, int nb,
                                                    int* __restrict__ rowptr, int N)
{
    __shared__ int buf[128];
    int t = threadIdx.x;
    int v = (t < nb) ? bsum[t] : 0;
    buf[t] = v;
    __syncthreads();
    for (int off = 1; off < 128; off <<= 1) {
        int u = (t >= off) ? buf[t - off] : 0;
        __syncthreads();
        buf[t] += u;
        __syncthreads();
    }
    if (t < nb) bsum[t] = buf[t] - v;   // exclusive
    if (t == 127) rowptr[N] = buf[127];
}

__global__ __launch_bounds__(256) void chunkscan_kernel(const int* __restrict__ cnt,
                                                        const int* __restrict__ bsum,
                                                        int* __restrict__ rowptr, int n)
{
    __shared__ int tsum[256];
    int b = blockIdx.x, t = threadIdx.x;
    int base = b * 1024 + t * 4;
    int c[4];
    int s = 0;
#pragma unroll
    for (int j = 0; j < 4; ++j) {
        int i = base + j;
        c[j] = (i < n) ? cnt[i] : 0;
        s += c[j];
    }
    tsum[t] = s;
    __syncthreads();
    for (int off = 1; off < 256; off <<= 1) {
        int u = (t >= off) ? tsum[t - off] : 0;
        __syncthreads();
        tsum[t] += u;
        __syncthreads();
    }
    int run = bsum[b] + tsum[t] - s;
#pragma unroll
    for (int j = 0; j < 4; ++j) {
        int i = base + j;
        if (i < n) { rowptr[i] = run; run += c[j]; }
    }
}

__global__ __launch_bounds__(256) void pass2_scatter_kernel(const int* __restrict__ pairs,
                                                            const int* __restrict__ bbase,
                                                            const int* __restrict__ rowptr,
                                                            int* __restrict__ csr_dst, int N)
{
    __shared__ int cur[BIN_ROWS];
    int b = blockIdx.x, t = threadIdx.x;
    int rowbase = b << BIN_SHIFT;
    int nrows = min(BIN_ROWS, N - rowbase);
    if (t < nrows) cur[t] = rowptr[rowbase + t];
    if (t + 256 < nrows) cur[t + 256] = rowptr[rowbase + t + 256];
    __syncthreads();
    int beg = bbase[b], end = bbase[b + 1];
    for (int i = beg + t; i < end; i += 256) {
        int p = pairs[i];
        int pos = atomicAdd(&cur[p >> DST_BITS], 1);
        csr_dst[pos] = p & DST_MASK;
    }
}

// ---------------------------------------------------------------------------
// Wt[n][k] = (fp16) W[k][n]
// ---------------------------------------------------------------------------
__global__ __launch_bounds__(256) void transpose16_kernel(const float* __restrict__ W,
                                                          _Float16* __restrict__ Wt,
                                                          int K, int Nw)
{
    int i = blockIdx.x * 256 + threadIdx.x;
    if (i < K * Nw) {
        int n = i / K, k = i - n * K;
        Wt[i] = (_Float16)W[(size_t)k * Nw + n];
    }
}

// ---------------------------------------------------------------------------
// MFMA f16 GEMM: C16[M,Nw] = A[M,K] @ Bt16[Nw,K]^T  (fp32 accum, fp16 out)
// CVTA: A fp32 converted during staging.
// FUSE_S: epilogue also computes ssrc[i] += h[i,:].avec[0:Nw-slice],
//         sdst[i] += h[i,:].avec[aoff:...] via lane-reduce + atomicAdd.
// ---------------------------------------------------------------------------
#define GBM 128
#define GBN 64
#define GBK 32
#define LDP 40

template <bool CVTA, bool FUSE_S>
__global__ __launch_bounds__(256) void gemm16_kernel(const void* __restrict__ Ap,
                                                     const _Float16* __restrict__ Bt,
                                                     _Float16* __restrict__ C,
                                                     int M, int Nw, int K,
                                                     const float* __restrict__ avec,
                                                     int aoff,
                                                     float* __restrict__ ssrc,
                                                     float* __restrict__ sdst)
{
    __shared__ __align__(16) _Float16 Ash[GBM * LDP];
    __shared__ __align__(16) _Float16 Bsh[GBN * LDP];
    const int tid = threadIdx.x;
    const int lane = tid & 63;
    const int w = tid >> 6;
    const int m0 = blockIdx.x * GBM;
    const int n0 = blockIdx.y * GBN;
    const int l15 = lane & 15;
    const int kq = lane >> 4;
    const int sr = tid >> 2;
    const int sc = tid & 3;

    f32x4 acc[2][4] = {};

    for (int k0 = 0; k0 < K; k0 += GBK) {
#pragma unroll
        for (int it = 0; it < 2; ++it) {
            int r = sr + it * 64;
            int gm = m0 + r;
            f16x8 v = {};
            if (gm < M) {
                if constexpr (CVTA) {
                    const float* Af = (const float*)Ap;
                    float4 u0 = *(const float4*)(Af + (size_t)gm * K + k0 + sc * 8);
                    float4 u1 = *(const float4*)(Af + (size_t)gm * K + k0 + sc * 8 + 4);
                    v[0] = (_Float16)u0.x; v[1] = (_Float16)u0.y;
                    v[2] = (_Float16)u0.z; v[3] = (_Float16)u0.w;
                    v[4] = (_Float16)u1.x; v[5] = (_Float16)u1.y;
                    v[6] = (_Float16)u1.z; v[7] = (_Float16)u1.w;
                } else {
                    v = *(const f16x8*)((const _Float16*)Ap + (size_t)gm * K + k0 + sc * 8);
                }
            }
            *(f16x8*)&Ash[r * LDP + sc * 8] = v;
        }
        {
            f16x8 v = *(const f16x8*)(Bt + (size_t)(n0 + sr) * K + k0 + sc * 8);
            *(f16x8*)&Bsh[sr * LDP + sc * 8] = v;
        }
        __syncthreads();

        f16x8 af[2], bf[4];
#pragma unroll
        for (int mt = 0; mt < 2; ++mt)
            af[mt] = *(const f16x8*)&Ash[(w * 32 + mt * 16 + l15) * LDP + kq * 8];
#pragma unroll
        for (int nt = 0; nt < 4; ++nt)
            bf[nt] = *(const f16x8*)&Bsh[(nt * 16 + l15) * LDP + kq * 8];
#pragma unroll
        for (int mt = 0; mt < 2; ++mt)
#pragma unroll
            for (int nt = 0; nt < 4; ++nt)
                acc[mt][nt] = __builtin_amdgcn_mfma_f32_16x16x32_f16(af[mt], bf[nt],
                                                                     acc[mt][nt], 0, 0, 0);
        __syncthreads();
    }

#pragma unroll
    for (int mt = 0; mt < 2; ++mt) {
#pragma unroll
        for (int r = 0; r < 4; ++r) {
            int gm = m0 + w * 32 + mt * 16 + kq * 4 + r;
            if (gm < M) {
#pragma unroll
                for (int nt = 0; nt < 4; ++nt)
                    C[(size_t)gm * Nw + n0 + nt * 16 + l15] = (_Float16)acc[mt][nt][r];
            }
        }
    }

    if constexpr (FUSE_S) {
        float as[4], ad[4];
#pragma unroll
        for (int nt = 0; nt < 4; ++nt) {
            int c = n0 + nt * 16 + l15;
            as[nt] = avec[c];
            ad[nt] = avec[aoff + c];
        }
#pragma unroll
        for (int mt = 0; mt < 2; ++mt) {
#pragma unroll
            for (int r = 0; r < 4; ++r) {
                float ps = 0.f, pd = 0.f;
#pragma unroll
                for (int nt = 0; nt < 4; ++nt) {
                    float v = acc[mt][nt][r];
                    ps += v * as[nt];
                    pd += v * ad[nt];
                }
#pragma unroll
                for (int off = 1; off < 16; off <<= 1) {
                    ps += __shfl_xor(ps, off);
                    pd += __shfl_xor(pd, off);
                }
                int gm = m0 + w * 32 + mt * 16 + kq * 4 + r;
                if (l15 == 0 && gm < M) {
                    atomicAdd(&ssrc[gm], ps);
                    atomicAdd(&sdst[gm], pd);
                }
            }
        }
    }
}

// ---------------------------------------------------------------------------
// FUSED per-row softmax + aggregation + ELU.
// One wave per row. deg<=128: weights+dst in per-wave LDS (float2, one read).
// Aggregation: 8 lanes/edge, 8 edges in flight (D=128 additionally processes
// 2 edges per lane per iteration). deg>128: 3-pass global spill fallback.
// ---------------------------------------------------------------------------
__device__ __forceinline__ float eluf(float x) { return x > 0.f ? x : expm1f(x); }

template <int D>
__global__ __launch_bounds__(256) void attnagg_kernel(const _Float16* __restrict__ h,
                                                      const float* __restrict__ ssrc,
                                                      const float* __restrict__ sdst,
                                                      const int* __restrict__ csr_dst,
                                                      const int* __restrict__ rowptr,
                                                      float* __restrict__ attn_spill,
                                                      _Float16* __restrict__ out, int nrows)
{
    constexpr int HPL = D / 8;             // halves per lane: 32 (D=256) or 16 (D=128)
    constexpr int NV = HPL / 8;            // f16x8 loads per edge-lane: 4 or 2
    __shared__ float2 wdbuf[4][128];
    int lane = threadIdx.x & 63;
    int wv = threadIdx.x >> 6;
    int row = blockIdx.x * 4 + wv;
    if (row >= nrows) return;
    int beg = rowptr[row], end = rowptr[row + 1];
    int deg = end - beg;
    bool small = (deg <= 128);

    if (deg > 0) {
        float ss = ssrc[row];
        if (small) {
            int e0 = beg + lane, e1 = e0 + 64;
            int d0 = 0, d1 = 0;
            float sc0 = -INFINITY, sc1 = -INFINITY;
            if (e0 < end) {
                d0 = csr_dst[e0];
                float sc = ss + sdst[d0];
                sc0 = (sc > 0.f) ? sc : LRELU_ALPHA * sc;
            }
            if (e1 < end) {
                d1 = csr_dst[e1];
                float sc = ss + sdst[d1];
                sc1 = (sc > 0.f) ? sc : LRELU_ALPHA * sc;
            }
            float m = fmaxf(sc0, sc1);
#pragma unroll
            for (int off = 32; off; off >>= 1) m = fmaxf(m, __shfl_xor(m, off));
            float ex0 = (e0 < end) ? expf(sc0 - m) : 0.f;
            float ex1 = (e1 < end) ? expf(sc1 - m) : 0.f;
            float z = ex0 + ex1;
#pragma unroll
            for (int off = 32; off; off >>= 1) z += __shfl_xor(z, off);
            float rz = 1.f / z;
            if (e0 < end) wdbuf[wv][lane] = make_float2(ex0 * rz, __int_as_float(d0));
            if (e1 < end) wdbuf[wv][64 + lane] = make_float2(ex1 * rz, __int_as_float(d1));
        } else {
            float m = -INFINITY;
            for (int e = beg + lane; e < end; e += 64) {
                float sc = ss + sdst[csr_dst[e]];
                sc = (sc > 0.f) ? sc : LRELU_ALPHA * sc;
                attn_spill[e] = sc;
                m = fmaxf(m, sc);
            }
#pragma unroll
            for (int off = 32; off; off >>= 1) m = fmaxf(m, __shfl_xor(m, off));
            float z = 0.f;
            for (int e = beg + lane; e < end; e += 64) {
                float ex = expf(attn_spill[e] - m);
                attn_spill[e] = ex;
                z += ex;
            }
#pragma unroll
            for (int off = 32; off; off >>= 1) z += __shfl_xor(z, off);
            float rz = 1.f / z;
            for (int e = beg + lane; e < end; e += 64) attn_spill[e] *= rz;
        }
    }

    // ---- aggregation: 8 lanes per edge, 8 edges in flight ----
    int sub = lane >> 3;
    int cl = lane & 7;
    float acc[HPL] = {};

    if (small) {
        if constexpr (D == 256) {
            for (int k = sub; k < deg; k += 8) {
                float2 wd = wdbuf[wv][k];
                float a = wd.x;
                int d = __float_as_int(wd.y);
                const _Float16* hp = h + (unsigned)(d * D) + cl * HPL;
                f16x8 vv[NV];
#pragma unroll
                for (int q = 0; q < NV; ++q) vv[q] = *(const f16x8*)(hp + q * 8);
#pragma unroll
                for (int q = 0; q < NV; ++q)
#pragma unroll
                    for (int j = 0; j < 8; ++j) acc[q * 8 + j] += a * (float)vv[q][j];
            }
        } else {
            // two edges per lane per iteration (k and k+8)
            int k = sub;
            for (; k + 8 < deg; k += 16) {
                float2 wdA = wdbuf[wv][k];
                float2 wdB = wdbuf[wv][k + 8];
                float aA = wdA.x, aB = wdB.x;
                int dA = __float_as_int(wdA.y), dB = __float_as_int(wdB.y);
                const _Float16* hpA = h + (unsigned)(dA * D) + cl * HPL;
                const _Float16* hpB = h + (unsigned)(dB * D) + cl * HPL;
                f16x8 vA[NV], vB[NV];
#pragma unroll
                for (int q = 0; q < NV; ++q) vA[q] = *(const f16x8*)(hpA + q * 8);
#pragma unroll
                for (int q = 0; q < NV; ++q) vB[q] = *(const f16x8*)(hpB + q * 8);
#pragma unroll
                for (int q = 0; q < NV; ++q)
#pragma unroll
                    for (int j = 0; j < 8; ++j) acc[q * 8 + j] += aA * (float)vA[q][j];
#pragma unroll
                for (int q = 0; q < NV; ++q)
#pragma unroll
                    for (int j = 0; j < 8; ++j) acc[q * 8 + j] += aB * (float)vB[q][j];
            }
            if (k < deg) {
                float2 wd = wdbuf[wv][k];
                float a = wd.x;
                int d = __float_as_int(wd.y);
                const _Float16* hp = h + (unsigned)(d * D) + cl * HPL;
                f16x8 vv[NV];
#pragma unroll
                for (int q = 0; q < NV; ++q) vv[q] = *(const f16x8*)(hp + q * 8);
#pragma unroll
                for (int q = 0; q < NV; ++q)
#pragma unroll
                    for (int j = 0; j < 8; ++j) acc[q * 8 + j] += a * (float)vv[q][j];
            }
        }
    } else {
        for (int k = sub; k < deg; k += 8) {
            float a = attn_spill[beg + k];
            int d = csr_dst[beg + k];
            const _Float16* hp = h + (unsigned)(d * D) + cl * HPL;
            f16x8 vv[NV];
#pragma unroll
            for (int q = 0; q < NV; ++q) vv[q] = *(const f16x8*)(hp + q * 8);
#pragma unroll
            for (int q = 0; q < NV; ++q)
#pragma unroll
                for (int j = 0; j < 8; ++j) acc[q * 8 + j] += a * (float)vv[q][j];
        }
    }

#pragma unroll
    for (int j = 0; j < HPL; ++j) {
        acc[j] += __shfl_xor(acc[j], 8);
        acc[j] += __shfl_xor(acc[j], 16);
        acc[j] += __shfl_xor(acc[j], 32);
    }
    if (sub == 0) {
        _Float16* op = out + (size_t)row * D + cl * HPL;
#pragma unroll
        for (int q = 0; q < NV; ++q) {
            f16x8 o;
#pragma unroll
            for (int j = 0; j < 8; ++j) o[j] = (_Float16)eluf(acc[q * 8 + j]);
            *(f16x8*)(op + q * 8) = o;
        }
    }
}

// ---------------------------------------------------------------------------
// final: logits = h1 @ lin_w + lin_b ; log_softmax; one wave per row
// ---------------------------------------------------------------------------
__global__ __launch_bounds__(256) void final16_kernel(const _Float16* __restrict__ h, // [N,128]
                                                      const float* __restrict__ lw,   // [128,40]
                                                      const float* __restrict__ lb,   // [40]
                                                      float* __restrict__ out, int nrows)
{
    __shared__ __align__(16) float rowbuf[4][128];
    int lane = threadIdx.x & 63;
    int wv = threadIdx.x >> 6;
    int row = blockIdx.x * 4 + wv;
    bool active = row < nrows;
    if (active) {
        f16x2 v = *(const f16x2*)&h[(size_t)row * 128 + lane * 2];
        rowbuf[wv][lane * 2] = (float)v[0];
        rowbuf[wv][lane * 2 + 1] = (float)v[1];
    }
    __syncthreads();
    float logit = 0.f;
    if (active && lane < 40) {
        float s = lb[lane];
        for (int k = 0; k < 128; ++k) s += rowbuf[wv][k] * lw[k * 40 + lane];
        logit = s;
    }
    float v = (active && lane < 40) ? logit : -INFINITY;
#pragma unroll
    for (int off = 32; off; off >>= 1) v = fmaxf(v, __shfl_xor(v, off));
    float ex = (active && lane < 40) ? expf(logit - v) : 0.f;
    float zs = ex;
#pragma unroll
    for (int off = 32; off; off >>= 1) zs += __shfl_xor(zs, off);
    if (active && lane < 40) out[(size_t)row * 40 + lane] = logit - v - logf(zs);
}

// ---------------------------------------------------------------------------
extern "C" void kernel_launch(void* const* d_in, const int* in_sizes, int n_in,
                              void* d_out, int out_size, void* d_ws, size_t ws_size,
                              hipStream_t stream)
{
    const float* x   = (const float*)d_in[0];   // [N,256]
    const int*  edge = (const int*)d_in[1];     // [2,E]
    const float* W0  = (const float*)d_in[2];   // [256,256]
    const float* a0  = (const float*)d_in[3];   // [512,1]
    const float* W1  = (const float*)d_in[4];   // [256,128]
    const float* a1  = (const float*)d_in[5];   // [256,1]
    const float* lw  = (const float*)d_in[6];   // [128,40]
    const float* lb  = (const float*)d_in[7];   // [40]
    float* out = (float*)d_out;

    const int N = in_sizes[0] / 256;
    const int E = in_sizes[1] / 2;
    const int* src = edge;
    const int* dst = edge + E;

    // ---- workspace layout ----
    _Float16* bufA = (_Float16*)d_ws;                 // N*256 halves (h0, then h1)
    _Float16* bufB = bufA + (size_t)N * 256;          // N*256 halves (h0', then h1')
    _Float16* W0t  = bufB + (size_t)N * 256;          // 256*256
    _Float16* W1t  = W0t + 256 * 256;                 // 128*256
    float* ssrc = (float*)(W1t + 128 * 256);          // N
    float* sdst = ssrc + N;                            // N
    float* attn = sdst + N;                            // E (spill for deg>128 rows)
    int* rowptr  = (int*)(attn + E);                   // N+1
    int* cnt     = rowptr + (N + 1);                   // N
    int* csr_dst = cnt + N;                            // E
    int* bsum    = csr_dst + E;                        // 128
    int* bhist   = bsum + 128;                         // 256
    int* bbase   = bhist + 256;                        // 257
    int* gcur    = bbase + 257;                        // 256
    // pairs aliases bufA: only live before gemm-0 writes bufA (stream-ordered)
    int* pairs   = (int*)bufA;                         // E ints (packed lrow|dst)

    const int rowBlocks = (N + 3) / 4;
    const int nb = (N + 1023) / 1024;                  // scan chunks (<=128)
    const int NB = (N + BIN_ROWS - 1) >> BIN_SHIFT;    // buckets (<=256)
    const int blocksE = (E + 4095) / 4096;

    // ---- CSR build (bucketed, packed) ----
    hipMemsetAsync(bhist, 0, 256 * sizeof(int), stream);
    bucket_count_kernel<<<blocksE, 256, 0, stream>>>(src, bhist, E);
    bucket_scan_kernel<<<1, 256, 0, stream>>>(bhist, bbase, gcur, E);
    pass1_bin_kernel<<<blocksE, 256, 0, stream>>>(src, dst, gcur, pairs, E);
    row_count_kernel<<<NB, 256, 0, stream>>>(pairs, bbase, cnt, N);
    bsum_kernel<<<nb, 256, 0, stream>>>(cnt, bsum, N);
    bscan_kernel<<<1, 128, 0, stream>>>(bsum, nb, rowptr, N);
    chunkscan_kernel<<<nb, 256, 0, stream>>>(cnt, bsum, rowptr, N);
    pass2_scatter_kernel<<<NB, 256, 0, stream>>>(pairs, bbase, rowptr, csr_dst, N);

    // ---- weight transposes (fp16) ----
    transpose16_kernel<<<(256 * 256 + 255) / 256, 256, 0, stream>>>(W0, W0t, 256, 256);
    transpose16_kernel<<<(128 * 256 + 255) / 256, 256, 0, stream>>>(W1, W1t, 256, 128);

    // ---- layer 0: d = 256 (A = x fp32, cvt in staging; s fused in epilogue) ----
    hipMemsetAsync(ssrc, 0, (size_t)2 * N * sizeof(float), stream);
    gemm16_kernel<true, true><<<dim3((N + GBM - 1) / GBM, 256 / GBN), 256, 0, stream>>>(
        x, W0t, bufA, N, 256, 256, a0, 256, ssrc, sdst);
    attnagg_kernel<256><<<rowBlocks, 256, 0, stream>>>(bufA, ssrc, sdst, csr_dst, rowptr, attn, bufB, N);

    // ---- layer 1: d = 128 ----
    hipMemsetAsync(ssrc, 0, (size_t)2 * N * sizeof(float), stream);
    gemm16_kernel<false, true><<<dim3((N + GBM - 1) / GBM, 128 / GBN), 256, 0, stream>>>(
        bufB, W1t, bufA, N, 128, 256, a1, 128, ssrc, sdst);
    attnagg_kernel<128><<<rowBlocks, 256, 0, stream>>>(bufA, ssrc, sdst, csr_dst, rowptr, attn, bufB, N);

    // ---- final linear + log_softmax ----
    final16_kernel<<<rowBlocks, 256, 0, stream>>>(bufB, lw, lb, out, N);
}

// Round 6
// 677.621 us; speedup vs baseline: 1.0240x; 1.0240x over previous
//
#include <hip/hip_runtime.h>
#include <cstddef>
#include <cstdint>

#define LRELU_ALPHA 0.2f
#define BIN_SHIFT 9
#define BIN_ROWS  (1 << BIN_SHIFT)   // 512 rows per bucket
// packed pair: (local_row << 17) | dst  -- requires N <= 131072 (N = 100000)
#define DST_BITS 17
#define DST_MASK ((1 << DST_BITS) - 1)

typedef _Float16 f16x8 __attribute__((ext_vector_type(8)));
typedef _Float16 f16x4 __attribute__((ext_vector_type(4)));
typedef _Float16 f16x2 __attribute__((ext_vector_type(2)));
typedef float    f32x4 __attribute__((ext_vector_type(4)));

// ---------------------------------------------------------------------------
// CSR build, locality-bucketed, packed pairs
// ---------------------------------------------------------------------------
__global__ __launch_bounds__(256) void bucket_count_kernel(const int* __restrict__ src,
                                                           int* __restrict__ bhist, int E)
{
    __shared__ int hist[256];
    int t = threadIdx.x;
    hist[t] = 0;
    __syncthreads();
    int base = blockIdx.x * 4096;
#pragma unroll
    for (int j = 0; j < 16; ++j) {
        int i = base + j * 256 + t;
        if (i < E) atomicAdd(&hist[src[i] >> BIN_SHIFT], 1);
    }
    __syncthreads();
    if (hist[t]) atomicAdd(&bhist[t], hist[t]);
}

__global__ __launch_bounds__(256) void bucket_scan_kernel(const int* __restrict__ bhist,
                                                          int* __restrict__ bbase,
                                                          int* __restrict__ gcur, int E)
{
    __shared__ int buf[256];
    int t = threadIdx.x;
    int v = bhist[t];
    buf[t] = v;
    __syncthreads();
    for (int off = 1; off < 256; off <<= 1) {
        int u = (t >= off) ? buf[t - off] : 0;
        __syncthreads();
        buf[t] += u;
        __syncthreads();
    }
    int excl = buf[t] - v;
    bbase[t] = excl;
    gcur[t] = excl;
    if (t == 255) bbase[256] = buf[255];
}

// bin packed (lrow|dst) into bucket-contiguous order
__global__ __launch_bounds__(256) void pass1_bin_kernel(const int* __restrict__ src,
                                                        const int* __restrict__ dst,
                                                        int* __restrict__ gcur,
                                                        int* __restrict__ pairs, int E)
{
    __shared__ int hist[256];
    __shared__ int cur[256];
    int t = threadIdx.x;
    hist[t] = 0;
    __syncthreads();
    int base = blockIdx.x * 4096;
    int s_[16], d_[16];
#pragma unroll
    for (int j = 0; j < 16; ++j) {
        int i = base + j * 256 + t;
        if (i < E) {
            s_[j] = src[i];
            d_[j] = dst[i];
            atomicAdd(&hist[s_[j] >> BIN_SHIFT], 1);
        } else s_[j] = -1;
    }
    __syncthreads();
    cur[t] = atomicAdd(&gcur[t], hist[t]);
    __syncthreads();
#pragma unroll
    for (int j = 0; j < 16; ++j) {
        if (s_[j] >= 0) {
            int pos = atomicAdd(&cur[s_[j] >> BIN_SHIFT], 1);
            pairs[pos] = ((s_[j] & (BIN_ROWS - 1)) << DST_BITS) | d_[j];
        }
    }
}

__global__ __launch_bounds__(256) void row_count_kernel(const int* __restrict__ pairs,
                                                        const int* __restrict__ bbase,
                                                        int* __restrict__ cnt, int N)
{
    __shared__ int c[BIN_ROWS];
    int b = blockIdx.x, t = threadIdx.x;
    int rowbase = b << BIN_SHIFT;
    int nrows = min(BIN_ROWS, N - rowbase);
    c[t] = 0; c[t + 256] = 0;
    __syncthreads();
    int beg = bbase[b], end = bbase[b + 1];
    for (int i = beg + t; i < end; i += 256)
        atomicAdd(&c[pairs[i] >> DST_BITS], 1);
    __syncthreads();
    if (t < nrows) cnt[rowbase + t] = c[t];
    if (t + 256 < nrows) cnt[rowbase + t + 256] = c[t + 256];
}

__global__ __launch_bounds__(256) void bsum_kernel(const int* __restrict__ cnt,
                                                   int* __restrict__ bsum, int n)
{
    __shared__ int red[4];
    int b = blockIdx.x, t = threadIdx.x;
    int base = b * 1024;
    int s = 0;
#pragma unroll
    for (int j = 0; j < 4; ++j) {
        int i = base + j * 256 + t;
        s += (i < n) ? cnt[i] : 0;
    }
#pragma unroll
    for (int off = 32; off; off >>= 1) s += __shfl_xor(s, off);
    if ((t & 63) == 0) red[t >> 6] = s;
    __syncthreads();
    if (t == 0) bsum[b] = red[0] + red[1] + red[2] + red[3];
}

__global__ __launch_bounds__(128) void bscan_kernel(int* __restrict__ bsum, int nb,
                                                    int* __restrict__ rowptr, int N)
{
    __shared__ int buf[128];
    int t = threadIdx.x;
    int v = (t < nb) ? bsum[t] : 0;
    buf[t] = v;
    __syncthreads();
    for (int off = 1; off < 128; off <<= 1) {
        int u = (t >= off) ? buf[t - off] : 0;
        __syncthreads();
        buf[t] += u;
        __syncthreads();
    }
    if (t < nb) bsum[t] = buf[t] - v;   // exclusive
    if (t == 127) rowptr[N] = buf[127];
}

__global__ __launch_bounds__(256) void chunkscan_kernel(const int* __restrict__ cnt,
                                                        const int* __restrict__ bsum,
                                                        int* __restrict__ rowptr, int n)
{
    __shared__ int tsum[256];
    int b = blockIdx.x, t = threadIdx.x;
    int base = b * 1024 + t * 4;
    int c[4];
    int s = 0;
#pragma unroll
    for (int j = 0; j < 4; ++j) {
        int i = base + j;
        c[j] = (i < n) ? cnt[i] : 0;
        s += c[j];
    }
    tsum[t] = s;
    __syncthreads();
    for (int off = 1; off < 256; off <<= 1) {
        int u = (t >= off) ? tsum[t - off] : 0;
        __syncthreads();
        tsum[t] += u;
        __syncthreads();
    }
    int run = bsum[b] + tsum[t] - s;
#pragma unroll
    for (int j = 0; j < 4; ++j) {
        int i = base + j;
        if (i < n) { rowptr[i] = run; run += c[j]; }
    }
}

__global__ __launch_bounds__(256) void pass2_scatter_kernel(const int* __restrict__ pairs,
                                                            const int* __restrict__ bbase,
                                                            const int* __restrict__ rowptr,
                                                            int* __restrict__ csr_dst, int N)
{
    __shared__ int cur[BIN_ROWS];
    int b = blockIdx.x, t = threadIdx.x;
    int rowbase = b << BIN_SHIFT;
    int nrows = min(BIN_ROWS, N - rowbase);
    if (t < nrows) cur[t] = rowptr[rowbase + t];
    if (t + 256 < nrows) cur[t + 256] = rowptr[rowbase + t + 256];
    __syncthreads();
    int beg = bbase[b], end = bbase[b + 1];
    for (int i = beg + t; i < end; i += 256) {
        int p = pairs[i];
        int pos = atomicAdd(&cur[p >> DST_BITS], 1);
        csr_dst[pos] = p & DST_MASK;
    }
}

// ---------------------------------------------------------------------------
// Wt[n][k] = (fp16) W[k][n]
// ---------------------------------------------------------------------------
__global__ __launch_bounds__(256) void transpose16_kernel(const float* __restrict__ W,
                                                          _Float16* __restrict__ Wt,
                                                          int K, int Nw)
{
    int i = blockIdx.x * 256 + threadIdx.x;
    if (i < K * Nw) {
        int n = i / K, k = i - n * K;
        Wt[i] = (_Float16)W[(size_t)k * Nw + n];
    }
}

// ---------------------------------------------------------------------------
// MFMA f16 GEMM: C16[M,Nw] = A[M,K] @ Bt16[Nw,K]^T  (fp32 accum, fp16 out)
// CVTA: A fp32 converted during staging.
// FUSE_S: epilogue computes ssrc/sdst dots via lane-reduce + atomicAdd.
// ---------------------------------------------------------------------------
#define GBM 128
#define GBN 64
#define GBK 32
#define LDP 40

template <bool CVTA, bool FUSE_S>
__global__ __launch_bounds__(256) void gemm16_kernel(const void* __restrict__ Ap,
                                                     const _Float16* __restrict__ Bt,
                                                     _Float16* __restrict__ C,
                                                     int M, int Nw, int K,
                                                     const float* __restrict__ avec,
                                                     int aoff,
                                                     float* __restrict__ ssrc,
                                                     float* __restrict__ sdst)
{
    __shared__ __align__(16) _Float16 Ash[GBM * LDP];
    __shared__ __align__(16) _Float16 Bsh[GBN * LDP];
    const int tid = threadIdx.x;
    const int lane = tid & 63;
    const int w = tid >> 6;
    const int m0 = blockIdx.x * GBM;
    const int n0 = blockIdx.y * GBN;
    const int l15 = lane & 15;
    const int kq = lane >> 4;
    const int sr = tid >> 2;
    const int sc = tid & 3;

    f32x4 acc[2][4] = {};

    for (int k0 = 0; k0 < K; k0 += GBK) {
#pragma unroll
        for (int it = 0; it < 2; ++it) {
            int r = sr + it * 64;
            int gm = m0 + r;
            f16x8 v = {};
            if (gm < M) {
                if constexpr (CVTA) {
                    const float* Af = (const float*)Ap;
                    float4 u0 = *(const float4*)(Af + (size_t)gm * K + k0 + sc * 8);
                    float4 u1 = *(const float4*)(Af + (size_t)gm * K + k0 + sc * 8 + 4);
                    v[0] = (_Float16)u0.x; v[1] = (_Float16)u0.y;
                    v[2] = (_Float16)u0.z; v[3] = (_Float16)u0.w;
                    v[4] = (_Float16)u1.x; v[5] = (_Float16)u1.y;
                    v[6] = (_Float16)u1.z; v[7] = (_Float16)u1.w;
                } else {
                    v = *(const f16x8*)((const _Float16*)Ap + (size_t)gm * K + k0 + sc * 8);
                }
            }
            *(f16x8*)&Ash[r * LDP + sc * 8] = v;
        }
        {
            f16x8 v = *(const f16x8*)(Bt + (size_t)(n0 + sr) * K + k0 + sc * 8);
            *(f16x8*)&Bsh[sr * LDP + sc * 8] = v;
        }
        __syncthreads();

        f16x8 af[2], bf[4];
#pragma unroll
        for (int mt = 0; mt < 2; ++mt)
            af[mt] = *(const f16x8*)&Ash[(w * 32 + mt * 16 + l15) * LDP + kq * 8];
#pragma unroll
        for (int nt = 0; nt < 4; ++nt)
            bf[nt] = *(const f16x8*)&Bsh[(nt * 16 + l15) * LDP + kq * 8];
#pragma unroll
        for (int mt = 0; mt < 2; ++mt)
#pragma unroll
            for (int nt = 0; nt < 4; ++nt)
                acc[mt][nt] = __builtin_amdgcn_mfma_f32_16x16x32_f16(af[mt], bf[nt],
                                                                     acc[mt][nt], 0, 0, 0);
        __syncthreads();
    }

#pragma unroll
    for (int mt = 0; mt < 2; ++mt) {
#pragma unroll
        for (int r = 0; r < 4; ++r) {
            int gm = m0 + w * 32 + mt * 16 + kq * 4 + r;
            if (gm < M) {
#pragma unroll
                for (int nt = 0; nt < 4; ++nt)
                    C[(size_t)gm * Nw + n0 + nt * 16 + l15] = (_Float16)acc[mt][nt][r];
            }
        }
    }

    if constexpr (FUSE_S) {
        float as[4], ad[4];
#pragma unroll
        for (int nt = 0; nt < 4; ++nt) {
            int c = n0 + nt * 16 + l15;
            as[nt] = avec[c];
            ad[nt] = avec[aoff + c];
        }
#pragma unroll
        for (int mt = 0; mt < 2; ++mt) {
#pragma unroll
            for (int r = 0; r < 4; ++r) {
                float ps = 0.f, pd = 0.f;
#pragma unroll
                for (int nt = 0; nt < 4; ++nt) {
                    float v = acc[mt][nt][r];
                    ps += v * as[nt];
                    pd += v * ad[nt];
                }
#pragma unroll
                for (int off = 1; off < 16; off <<= 1) {
                    ps += __shfl_xor(ps, off);
                    pd += __shfl_xor(pd, off);
                }
                int gm = m0 + w * 32 + mt * 16 + kq * 4 + r;
                if (l15 == 0 && gm < M) {
                    atomicAdd(&ssrc[gm], ps);
                    atomicAdd(&sdst[gm], pd);
                }
            }
        }
    }
}

// ---------------------------------------------------------------------------
// FUSED per-row softmax + aggregation + ELU.
// One wave per row; 16 lanes/edge, 2 edges unrolled; packed f16 FMA
// accumulate (v_pk_fma_f16: 2 elems/VALU-op vs cvt+fma's 0.5).
// deg<=128: weights+dst in per-wave LDS. deg>128: global spill fallback.
// ---------------------------------------------------------------------------
__device__ __forceinline__ float eluf(float x) { return x > 0.f ? x : expm1f(x); }

union h2u { f16x2 h; unsigned u; };
__device__ __forceinline__ unsigned pkadd(unsigned a, unsigned b)
{
    h2u x, y; x.u = a; y.u = b; x.h += y.h; return x.u;
}

template <int D>
__global__ __launch_bounds__(256) void attnagg_kernel(const _Float16* __restrict__ h,
                                                      const float* __restrict__ ssrc,
                                                      const float* __restrict__ sdst,
                                                      const int* __restrict__ csr_dst,
                                                      const int* __restrict__ rowptr,
                                                      float* __restrict__ attn_spill,
                                                      _Float16* __restrict__ out, int nrows)
{
    constexpr int HPL = D / 16;            // halves per lane: 16 (D=256) or 8 (D=128)
    constexpr int NV = HPL / 8;            // f16x8 vectors per lane: 2 or 1
    __shared__ float2 wdbuf[4][128];
    int lane = threadIdx.x & 63;
    int wv = threadIdx.x >> 6;
    int row = blockIdx.x * 4 + wv;
    if (row >= nrows) return;
    int beg = rowptr[row], end = rowptr[row + 1];
    int deg = end - beg;
    bool small = (deg <= 128);

    if (deg > 0) {
        float ss = ssrc[row];
        if (small) {
            int e0 = beg + lane, e1 = e0 + 64;
            int d0 = 0, d1 = 0;
            float sc0 = -INFINITY, sc1 = -INFINITY;
            if (e0 < end) {
                d0 = csr_dst[e0];
                float sc = ss + sdst[d0];
                sc0 = (sc > 0.f) ? sc : LRELU_ALPHA * sc;
            }
            if (e1 < end) {
                d1 = csr_dst[e1];
                float sc = ss + sdst[d1];
                sc1 = (sc > 0.f) ? sc : LRELU_ALPHA * sc;
            }
            float m = fmaxf(sc0, sc1);
#pragma unroll
            for (int off = 32; off; off >>= 1) m = fmaxf(m, __shfl_xor(m, off));
            float ex0 = (e0 < end) ? expf(sc0 - m) : 0.f;
            float ex1 = (e1 < end) ? expf(sc1 - m) : 0.f;
            float z = ex0 + ex1;
#pragma unroll
            for (int off = 32; off; off >>= 1) z += __shfl_xor(z, off);
            float rz = 1.f / z;
            if (e0 < end) wdbuf[wv][lane] = make_float2(ex0 * rz, __int_as_float(d0));
            if (e1 < end) wdbuf[wv][64 + lane] = make_float2(ex1 * rz, __int_as_float(d1));
        } else {
            float m = -INFINITY;
            for (int e = beg + lane; e < end; e += 64) {
                float sc = ss + sdst[csr_dst[e]];
                sc = (sc > 0.f) ? sc : LRELU_ALPHA * sc;
                attn_spill[e] = sc;
                m = fmaxf(m, sc);
            }
#pragma unroll
            for (int off = 32; off; off >>= 1) m = fmaxf(m, __shfl_xor(m, off));
            float z = 0.f;
            for (int e = beg + lane; e < end; e += 64) {
                float ex = expf(attn_spill[e] - m);
                attn_spill[e] = ex;
                z += ex;
            }
#pragma unroll
            for (int off = 32; off; off >>= 1) z += __shfl_xor(z, off);
            float rz = 1.f / z;
            for (int e = beg + lane; e < end; e += 64) attn_spill[e] *= rz;
        }
    }

    // ---- aggregation: 16 lanes/edge, 4 edges in flight, 2-edge unroll ----
    int sub = lane >> 4;          // 0..3
    int cl = lane & 15;
    const _Float16* hbase = h + cl * HPL;
    f16x8 acc[NV] = {};

    if (small) {
        int k = sub;
        for (; k + 4 < deg; k += 8) {
            float2 wdA = wdbuf[wv][k];
            float2 wdB = wdbuf[wv][k + 4];
            const _Float16* hpA = hbase + ((unsigned)__float_as_int(wdA.y) * D);
            const _Float16* hpB = hbase + ((unsigned)__float_as_int(wdB.y) * D);
            f16x8 vA[NV], vB[NV];
#pragma unroll
            for (int q = 0; q < NV; ++q) vA[q] = *(const f16x8*)(hpA + q * 8);
#pragma unroll
            for (int q = 0; q < NV; ++q) vB[q] = *(const f16x8*)(hpB + q * 8);
            _Float16 whA = (_Float16)wdA.x, whB = (_Float16)wdB.x;
            f16x8 a8A = {whA, whA, whA, whA, whA, whA, whA, whA};
            f16x8 a8B = {whB, whB, whB, whB, whB, whB, whB, whB};
#pragma unroll
            for (int q = 0; q < NV; ++q) acc[q] += vA[q] * a8A;
#pragma unroll
            for (int q = 0; q < NV; ++q) acc[q] += vB[q] * a8B;
        }
        if (k < deg) {
            float2 wd = wdbuf[wv][k];
            const _Float16* hp = hbase + ((unsigned)__float_as_int(wd.y) * D);
            f16x8 vv[NV];
#pragma unroll
            for (int q = 0; q < NV; ++q) vv[q] = *(const f16x8*)(hp + q * 8);
            _Float16 wh = (_Float16)wd.x;
            f16x8 a8 = {wh, wh, wh, wh, wh, wh, wh, wh};
#pragma unroll
            for (int q = 0; q < NV; ++q) acc[q] += vv[q] * a8;
        }
    } else {
        for (int k = sub; k < deg; k += 4) {
            float a = attn_spill[beg + k];
            int d = csr_dst[beg + k];
            const _Float16* hp = hbase + ((unsigned)d * D);
            f16x8 vv[NV];
#pragma unroll
            for (int q = 0; q < NV; ++q) vv[q] = *(const f16x8*)(hp + q * 8);
            _Float16 wh = (_Float16)a;
            f16x8 a8 = {wh, wh, wh, wh, wh, wh, wh, wh};
#pragma unroll
            for (int q = 0; q < NV; ++q) acc[q] += vv[q] * a8;
        }
    }

    // packed reduce across the 4 sub-groups (lanes differing in bits 4,5)
    union { f16x8 v; unsigned w[4]; } A[NV];
#pragma unroll
    for (int q = 0; q < NV; ++q) A[q].v = acc[q];
#pragma unroll
    for (int q = 0; q < NV; ++q)
#pragma unroll
        for (int i = 0; i < 4; ++i) {
            unsigned u = A[q].w[i];
            u = pkadd(u, (unsigned)__shfl_xor((int)u, 16));
            u = pkadd(u, (unsigned)__shfl_xor((int)u, 32));
            A[q].w[i] = u;
        }
    if (sub == 0) {
        _Float16* op = out + (size_t)row * D + cl * HPL;
#pragma unroll
        for (int q = 0; q < NV; ++q) {
            f16x8 o;
#pragma unroll
            for (int j = 0; j < 8; ++j) o[j] = (_Float16)eluf((float)A[q].v[j]);
            *(f16x8*)(op + q * 8) = o;
        }
    }
}

// ---------------------------------------------------------------------------
// final: logits = h1 @ lin_w + lin_b ; log_softmax; one wave per row
// ---------------------------------------------------------------------------
__global__ __launch_bounds__(256) void final16_kernel(const _Float16* __restrict__ h, // [N,128]
                                                      const float* __restrict__ lw,   // [128,40]
                                                      const float* __restrict__ lb,   // [40]
                                                      float* __restrict__ out, int nrows)
{
    __shared__ __align__(16) float rowbuf[4][128];
    int lane = threadIdx.x & 63;
    int wv = threadIdx.x >> 6;
    int row = blockIdx.x * 4 + wv;
    bool active = row < nrows;
    if (active) {
        f16x2 v = *(const f16x2*)&h[(size_t)row * 128 + lane * 2];
        rowbuf[wv][lane * 2] = (float)v[0];
        rowbuf[wv][lane * 2 + 1] = (float)v[1];
    }
    __syncthreads();
    float logit = 0.f;
    if (active && lane < 40) {
        float s = lb[lane];
        for (int k = 0; k < 128; ++k) s += rowbuf[wv][k] * lw[k * 40 + lane];
        logit = s;
    }
    float v = (active && lane < 40) ? logit : -INFINITY;
#pragma unroll
    for (int off = 32; off; off >>= 1) v = fmaxf(v, __shfl_xor(v, off));
    float ex = (active && lane < 40) ? expf(logit - v) : 0.f;
    float zs = ex;
#pragma unroll
    for (int off = 32; off; off >>= 1) zs += __shfl_xor(zs, off);
    if (active && lane < 40) out[(size_t)row * 40 + lane] = logit - v - logf(zs);
}

// ---------------------------------------------------------------------------
extern "C" void kernel_launch(void* const* d_in, const int* in_sizes, int n_in,
                              void* d_out, int out_size, void* d_ws, size_t ws_size,
                              hipStream_t stream)
{
    const float* x   = (const float*)d_in[0];   // [N,256]
    const int*  edge = (const int*)d_in[1];     // [2,E]
    const float* W0  = (const float*)d_in[2];   // [256,256]
    const float* a0  = (const float*)d_in[3];   // [512,1]
    const float* W1  = (const float*)d_in[4];   // [256,128]
    const float* a1  = (const float*)d_in[5];   // [256,1]
    const float* lw  = (const float*)d_in[6];   // [128,40]
    const float* lb  = (const float*)d_in[7];   // [40]
    float* out = (float*)d_out;

    const int N = in_sizes[0] / 256;
    const int E = in_sizes[1] / 2;
    const int* src = edge;
    const int* dst = edge + E;

    // ---- workspace layout ----
    _Float16* bufA = (_Float16*)d_ws;                 // N*256 halves (h0, then h1)
    _Float16* bufB = bufA + (size_t)N * 256;          // N*256 halves (h0', then h1')
    _Float16* W0t  = bufB + (size_t)N * 256;          // 256*256
    _Float16* W1t  = W0t + 256 * 256;                 // 128*256
    float* ssrc = (float*)(W1t + 128 * 256);          // N
    float* sdst = ssrc + N;                            // N
    float* attn = sdst + N;                            // E (spill for deg>128 rows)
    int* rowptr  = (int*)(attn + E);                   // N+1
    int* cnt     = rowptr + (N + 1);                   // N
    int* csr_dst = cnt + N;                            // E
    int* bsum    = csr_dst + E;                        // 128
    int* bhist   = bsum + 128;                         // 256
    int* bbase   = bhist + 256;                        // 257
    int* gcur    = bbase + 257;                        // 256
    // pairs aliases bufA: only live before gemm-0 writes bufA (stream-ordered)
    int* pairs   = (int*)bufA;                         // E ints (packed lrow|dst)

    const int rowBlocks = (N + 3) / 4;
    const int nb = (N + 1023) / 1024;                  // scan chunks (<=128)
    const int NB = (N + BIN_ROWS - 1) >> BIN_SHIFT;    // buckets (<=256)
    const int blocksE = (E + 4095) / 4096;

    // ---- CSR build (bucketed, packed) ----
    hipMemsetAsync(bhist, 0, 256 * sizeof(int), stream);
    bucket_count_kernel<<<blocksE, 256, 0, stream>>>(src, bhist, E);
    bucket_scan_kernel<<<1, 256, 0, stream>>>(bhist, bbase, gcur, E);
    pass1_bin_kernel<<<blocksE, 256, 0, stream>>>(src, dst, gcur, pairs, E);
    row_count_kernel<<<NB, 256, 0, stream>>>(pairs, bbase, cnt, N);
    bsum_kernel<<<nb, 256, 0, stream>>>(cnt, bsum, N);
    bscan_kernel<<<1, 128, 0, stream>>>(bsum, nb, rowptr, N);
    chunkscan_kernel<<<nb, 256, 0, stream>>>(cnt, bsum, rowptr, N);
    pass2_scatter_kernel<<<NB, 256, 0, stream>>>(pairs, bbase, rowptr, csr_dst, N);

    // ---- weight transposes (fp16) ----
    transpose16_kernel<<<(256 * 256 + 255) / 256, 256, 0, stream>>>(W0, W0t, 256, 256);
    transpose16_kernel<<<(128 * 256 + 255) / 256, 256, 0, stream>>>(W1, W1t, 256, 128);

    // ---- layer 0: d = 256 (A = x fp32, cvt in staging; s fused in epilogue) ----
    hipMemsetAsync(ssrc, 0, (size_t)2 * N * sizeof(float), stream);
    gemm16_kernel<true, true><<<dim3((N + GBM - 1) / GBM, 256 / GBN), 256, 0, stream>>>(
        x, W0t, bufA, N, 256, 256, a0, 256, ssrc, sdst);
    attnagg_kernel<256><<<rowBlocks, 256, 0, stream>>>(bufA, ssrc, sdst, csr_dst, rowptr, attn, bufB, N);

    // ---- layer 1: d = 128 ----
    hipMemsetAsync(ssrc, 0, (size_t)2 * N * sizeof(float), stream);
    gemm16_kernel<false, true><<<dim3((N + GBM - 1) / GBM, 128 / GBN), 256, 0, stream>>>(
        bufB, W1t, bufA, N, 128, 256, a1, 128, ssrc, sdst);
    attnagg_kernel<128><<<rowBlocks, 256, 0, stream>>>(bufA, ssrc, sdst, csr_dst, rowptr, attn, bufB, N);

    // ---- final linear + log_softmax ----
    final16_kernel<<<rowBlocks, 256, 0, stream>>>(bufB, lw, lb, out, N);
}

// Round 7
// 647.576 us; speedup vs baseline: 1.0715x; 1.0464x over previous
//
#include <hip/hip_runtime.h>
#include <cstddef>
#include <cstdint>

#define LRELU_ALPHA 0.2f
#define BIN_SHIFT 9
#define BIN_ROWS  (1 << BIN_SHIFT)   // 512 rows per bucket
// packed pair: (local_row << 17) | dst  -- requires N <= 131072 (N = 100000)
#define DST_BITS 17
#define DST_MASK ((1 << DST_BITS) - 1)

typedef _Float16 f16x8 __attribute__((ext_vector_type(8)));
typedef _Float16 f16x4 __attribute__((ext_vector_type(4)));
typedef _Float16 f16x2 __attribute__((ext_vector_type(2)));
typedef float    f32x4 __attribute__((ext_vector_type(4)));

// ---------------------------------------------------------------------------
// CSR build, locality-bucketed, packed pairs
// ---------------------------------------------------------------------------
__global__ __launch_bounds__(256) void bucket_count_kernel(const int* __restrict__ src,
                                                           int* __restrict__ bhist, int E)
{
    __shared__ int hist[256];
    int t = threadIdx.x;
    hist[t] = 0;
    __syncthreads();
    int base = blockIdx.x * 4096;
#pragma unroll
    for (int j = 0; j < 16; ++j) {
        int i = base + j * 256 + t;
        if (i < E) atomicAdd(&hist[src[i] >> BIN_SHIFT], 1);
    }
    __syncthreads();
    if (hist[t]) atomicAdd(&bhist[t], hist[t]);
}

__global__ __launch_bounds__(256) void bucket_scan_kernel(const int* __restrict__ bhist,
                                                          int* __restrict__ bbase,
                                                          int* __restrict__ gcur, int E)
{
    __shared__ int buf[256];
    int t = threadIdx.x;
    int v = bhist[t];
    buf[t] = v;
    __syncthreads();
    for (int off = 1; off < 256; off <<= 1) {
        int u = (t >= off) ? buf[t - off] : 0;
        __syncthreads();
        buf[t] += u;
        __syncthreads();
    }
    int excl = buf[t] - v;
    bbase[t] = excl;
    gcur[t] = excl;
    if (t == 255) bbase[256] = buf[255];
}

// bin packed (lrow|dst) into bucket-contiguous order
__global__ __launch_bounds__(256) void pass1_bin_kernel(const int* __restrict__ src,
                                                        const int* __restrict__ dst,
                                                        int* __restrict__ gcur,
                                                        int* __restrict__ pairs, int E)
{
    __shared__ int hist[256];
    __shared__ int cur[256];
    int t = threadIdx.x;
    hist[t] = 0;
    __syncthreads();
    int base = blockIdx.x * 4096;
    int s_[16], d_[16];
#pragma unroll
    for (int j = 0; j < 16; ++j) {
        int i = base + j * 256 + t;
        if (i < E) {
            s_[j] = src[i];
            d_[j] = dst[i];
            atomicAdd(&hist[s_[j] >> BIN_SHIFT], 1);
        } else s_[j] = -1;
    }
    __syncthreads();
    cur[t] = atomicAdd(&gcur[t], hist[t]);
    __syncthreads();
#pragma unroll
    for (int j = 0; j < 16; ++j) {
        if (s_[j] >= 0) {
            int pos = atomicAdd(&cur[s_[j] >> BIN_SHIFT], 1);
            pairs[pos] = ((s_[j] & (BIN_ROWS - 1)) << DST_BITS) | d_[j];
        }
    }
}

__global__ __launch_bounds__(256) void row_count_kernel(const int* __restrict__ pairs,
                                                        const int* __restrict__ bbase,
                                                        int* __restrict__ cnt, int N)
{
    __shared__ int c[BIN_ROWS];
    int b = blockIdx.x, t = threadIdx.x;
    int rowbase = b << BIN_SHIFT;
    int nrows = min(BIN_ROWS, N - rowbase);
    c[t] = 0; c[t + 256] = 0;
    __syncthreads();
    int beg = bbase[b], end = bbase[b + 1];
    for (int i = beg + t; i < end; i += 256)
        atomicAdd(&c[pairs[i] >> DST_BITS], 1);
    __syncthreads();
    if (t < nrows) cnt[rowbase + t] = c[t];
    if (t + 256 < nrows) cnt[rowbase + t + 256] = c[t + 256];
}

__global__ __launch_bounds__(256) void bsum_kernel(const int* __restrict__ cnt,
                                                   int* __restrict__ bsum, int n)
{
    __shared__ int red[4];
    int b = blockIdx.x, t = threadIdx.x;
    int base = b * 1024;
    int s = 0;
#pragma unroll
    for (int j = 0; j < 4; ++j) {
        int i = base + j * 256 + t;
        s += (i < n) ? cnt[i] : 0;
    }
#pragma unroll
    for (int off = 32; off; off >>= 1) s += __shfl_xor(s, off);
    if ((t & 63) == 0) red[t >> 6] = s;
    __syncthreads();
    if (t == 0) bsum[b] = red[0] + red[1] + red[2] + red[3];
}

__global__ __launch_bounds__(128) void bscan_kernel(int* __restrict__ bsum, int nb,
                                                    int* __restrict__ rowptr, int N)
{
    __shared__ int buf[128];
    int t = threadIdx.x;
    int v = (t < nb) ? bsum[t] : 0;
    buf[t] = v;
    __syncthreads();
    for (int off = 1; off < 128; off <<= 1) {
        int u = (t >= off) ? buf[t - off] : 0;
        __syncthreads();
        buf[t] += u;
        __syncthreads();
    }
    if (t < nb) bsum[t] = buf[t] - v;   // exclusive
    if (t == 127) rowptr[N] = buf[127];
}

__global__ __launch_bounds__(256) void chunkscan_kernel(const int* __restrict__ cnt,
                                                        const int* __restrict__ bsum,
                                                        int* __restrict__ rowptr, int n)
{
    __shared__ int tsum[256];
    int b = blockIdx.x, t = threadIdx.x;
    int base = b * 1024 + t * 4;
    int c[4];
    int s = 0;
#pragma unroll
    for (int j = 0; j < 4; ++j) {
        int i = base + j;
        c[j] = (i < n) ? cnt[i] : 0;
        s += c[j];
    }
    tsum[t] = s;
    __syncthreads();
    for (int off = 1; off < 256; off <<= 1) {
        int u = (t >= off) ? tsum[t - off] : 0;
        __syncthreads();
        tsum[t] += u;
        __syncthreads();
    }
    int run = bsum[b] + tsum[t] - s;
#pragma unroll
    for (int j = 0; j < 4; ++j) {
        int i = base + j;
        if (i < n) { rowptr[i] = run; run += c[j]; }
    }
}

__global__ __launch_bounds__(256) void pass2_scatter_kernel(const int* __restrict__ pairs,
                                                            const int* __restrict__ bbase,
                                                            const int* __restrict__ rowptr,
                                                            int* __restrict__ csr_dst, int N)
{
    __shared__ int cur[BIN_ROWS];
    int b = blockIdx.x, t = threadIdx.x;
    int rowbase = b << BIN_SHIFT;
    int nrows = min(BIN_ROWS, N - rowbase);
    if (t < nrows) cur[t] = rowptr[rowbase + t];
    if (t + 256 < nrows) cur[t + 256] = rowptr[rowbase + t + 256];
    __syncthreads();
    int beg = bbase[b], end = bbase[b + 1];
    for (int i = beg + t; i < end; i += 256) {
        int p = pairs[i];
        int pos = atomicAdd(&cur[p >> DST_BITS], 1);
        csr_dst[pos] = p & DST_MASK;
    }
}

// ---------------------------------------------------------------------------
// Wt[n][k] = (fp16) W[k][n]
// ---------------------------------------------------------------------------
__global__ __launch_bounds__(256) void transpose16_kernel(const float* __restrict__ W,
                                                          _Float16* __restrict__ Wt,
                                                          int K, int Nw)
{
    int i = blockIdx.x * 256 + threadIdx.x;
    if (i < K * Nw) {
        int n = i / K, k = i - n * K;
        Wt[i] = (_Float16)W[(size_t)k * Nw + n];
    }
}

// ---------------------------------------------------------------------------
// MFMA f16 GEMM v2: one block-column covers ALL Nw columns (GBN = Nw) so the
// A matrix is streamed exactly ONCE.  GBM=64, 4 waves, wave w owns a
// 64 x (GBN/4) output slice.  B tile (GBN x 32) fully LDS-staged per k-step.
// CVTA: A fp32 converted during staging.  FUSE_S: epilogue computes
// ssrc/sdst dots via 16-lane reduce + atomicAdd.
// ---------------------------------------------------------------------------
#define GBM 64
#define GBK 32
#define LDP 40

template <bool CVTA, bool FUSE_S, int GBN>
__global__ __launch_bounds__(256) void gemm16_kernel(const void* __restrict__ Ap,
                                                     const _Float16* __restrict__ Bt,
                                                     _Float16* __restrict__ C,
                                                     int M, int K,
                                                     const float* __restrict__ avec,
                                                     int aoff,
                                                     float* __restrict__ ssrc,
                                                     float* __restrict__ sdst)
{
    constexpr int NT = GBN / 64;          // n-frags per wave: 4 (256) or 2 (128)
    __shared__ __align__(16) _Float16 Ash[GBM * LDP];
    __shared__ __align__(16) _Float16 Bsh[GBN * LDP];
    const int tid = threadIdx.x;
    const int lane = tid & 63;
    const int w = tid >> 6;               // 0..3
    const int m0 = blockIdx.x * GBM;
    const int l15 = lane & 15;
    const int kq = lane >> 4;
    const int sr = tid >> 2;              // 0..63
    const int sc = tid & 3;
    const int wc = w * (GBN / 4);         // wave col base

    f32x4 acc[4][NT] = {};

    for (int k0 = 0; k0 < K; k0 += GBK) {
        {   // A: 64 rows x 32 halves
            int gm = m0 + sr;
            f16x8 v = {};
            if (gm < M) {
                if constexpr (CVTA) {
                    const float* Af = (const float*)Ap;
                    float4 u0 = *(const float4*)(Af + (size_t)gm * K + k0 + sc * 8);
                    float4 u1 = *(const float4*)(Af + (size_t)gm * K + k0 + sc * 8 + 4);
                    v[0] = (_Float16)u0.x; v[1] = (_Float16)u0.y;
                    v[2] = (_Float16)u0.z; v[3] = (_Float16)u0.w;
                    v[4] = (_Float16)u1.x; v[5] = (_Float16)u1.y;
                    v[6] = (_Float16)u1.z; v[7] = (_Float16)u1.w;
                } else {
                    v = *(const f16x8*)((const _Float16*)Ap + (size_t)gm * K + k0 + sc * 8);
                }
            }
            *(f16x8*)&Ash[sr * LDP + sc * 8] = v;
        }
#pragma unroll
        for (int it = 0; it < GBN / 64; ++it) {   // B: GBN rows x 32 halves
            int r = sr + it * 64;
            f16x8 v = *(const f16x8*)(Bt + (size_t)r * K + k0 + sc * 8);
            *(f16x8*)&Bsh[r * LDP + sc * 8] = v;
        }
        __syncthreads();

        f16x8 af[4], bf[NT];
#pragma unroll
        for (int mt = 0; mt < 4; ++mt)
            af[mt] = *(const f16x8*)&Ash[(mt * 16 + l15) * LDP + kq * 8];
#pragma unroll
        for (int nt = 0; nt < NT; ++nt)
            bf[nt] = *(const f16x8*)&Bsh[(wc + nt * 16 + l15) * LDP + kq * 8];
#pragma unroll
        for (int mt = 0; mt < 4; ++mt)
#pragma unroll
            for (int nt = 0; nt < NT; ++nt)
                acc[mt][nt] = __builtin_amdgcn_mfma_f32_16x16x32_f16(af[mt], bf[nt],
                                                                     acc[mt][nt], 0, 0, 0);
        __syncthreads();
    }

#pragma unroll
    for (int mt = 0; mt < 4; ++mt) {
#pragma unroll
        for (int r = 0; r < 4; ++r) {
            int gm = m0 + mt * 16 + kq * 4 + r;
            if (gm < M) {
#pragma unroll
                for (int nt = 0; nt < NT; ++nt)
                    C[(size_t)gm * GBN + wc + nt * 16 + l15] = (_Float16)acc[mt][nt][r];
            }
        }
    }

    if constexpr (FUSE_S) {
        float as[NT], ad[NT];
#pragma unroll
        for (int nt = 0; nt < NT; ++nt) {
            int c = wc + nt * 16 + l15;
            as[nt] = avec[c];
            ad[nt] = avec[aoff + c];
        }
#pragma unroll
        for (int mt = 0; mt < 4; ++mt) {
#pragma unroll
            for (int r = 0; r < 4; ++r) {
                float ps = 0.f, pd = 0.f;
#pragma unroll
                for (int nt = 0; nt < NT; ++nt) {
                    float v = acc[mt][nt][r];
                    ps += v * as[nt];
                    pd += v * ad[nt];
                }
#pragma unroll
                for (int off = 1; off < 16; off <<= 1) {
                    ps += __shfl_xor(ps, off);
                    pd += __shfl_xor(pd, off);
                }
                int gm = m0 + mt * 16 + kq * 4 + r;
                if (l15 == 0 && gm < M) {
                    atomicAdd(&ssrc[gm], ps);
                    atomicAdd(&sdst[gm], pd);
                }
            }
        }
    }
}

// ---------------------------------------------------------------------------
// FUSED per-row softmax + aggregation + ELU.
// One wave per row; 16 lanes/edge; 4-edge-deep gather pipeline (8 outstanding
// 16B loads/lane); packed f16 FMA accumulate.
// deg<=128: weights+dst in per-wave LDS. deg>128: global spill fallback.
// ---------------------------------------------------------------------------
__device__ __forceinline__ float eluf(float x) { return x > 0.f ? x : expm1f(x); }

union h2u { f16x2 h; unsigned u; };
__device__ __forceinline__ unsigned pkadd(unsigned a, unsigned b)
{
    h2u x, y; x.u = a; y.u = b; x.h += y.h; return x.u;
}

template <int D>
__global__ __launch_bounds__(256) void attnagg_kernel(const _Float16* __restrict__ h,
                                                      const float* __restrict__ ssrc,
                                                      const float* __restrict__ sdst,
                                                      const int* __restrict__ csr_dst,
                                                      const int* __restrict__ rowptr,
                                                      float* __restrict__ attn_spill,
                                                      _Float16* __restrict__ out, int nrows)
{
    constexpr int HPL = D / 16;            // halves per lane: 16 (D=256) or 8 (D=128)
    constexpr int NV = HPL / 8;            // f16x8 vectors per lane: 2 or 1
    __shared__ float2 wdbuf[4][128];
    int lane = threadIdx.x & 63;
    int wv = threadIdx.x >> 6;
    int row = blockIdx.x * 4 + wv;
    if (row >= nrows) return;
    int beg = rowptr[row], end = rowptr[row + 1];
    int deg = end - beg;
    bool small = (deg <= 128);

    if (deg > 0) {
        float ss = ssrc[row];
        if (small) {
            int e0 = beg + lane, e1 = e0 + 64;
            int d0 = 0, d1 = 0;
            float sc0 = -INFINITY, sc1 = -INFINITY;
            if (e0 < end) {
                d0 = csr_dst[e0];
                float sc = ss + sdst[d0];
                sc0 = (sc > 0.f) ? sc : LRELU_ALPHA * sc;
            }
            if (e1 < end) {
                d1 = csr_dst[e1];
                float sc = ss + sdst[d1];
                sc1 = (sc > 0.f) ? sc : LRELU_ALPHA * sc;
            }
            float m = fmaxf(sc0, sc1);
#pragma unroll
            for (int off = 32; off; off >>= 1) m = fmaxf(m, __shfl_xor(m, off));
            float ex0 = (e0 < end) ? expf(sc0 - m) : 0.f;
            float ex1 = (e1 < end) ? expf(sc1 - m) : 0.f;
            float z = ex0 + ex1;
#pragma unroll
            for (int off = 32; off; off >>= 1) z += __shfl_xor(z, off);
            float rz = 1.f / z;
            if (e0 < end) wdbuf[wv][lane] = make_float2(ex0 * rz, __int_as_float(d0));
            if (e1 < end) wdbuf[wv][64 + lane] = make_float2(ex1 * rz, __int_as_float(d1));
        } else {
            float m = -INFINITY;
            for (int e = beg + lane; e < end; e += 64) {
                float sc = ss + sdst[csr_dst[e]];
                sc = (sc > 0.f) ? sc : LRELU_ALPHA * sc;
                attn_spill[e] = sc;
                m = fmaxf(m, sc);
            }
#pragma unroll
            for (int off = 32; off; off >>= 1) m = fmaxf(m, __shfl_xor(m, off));
            float z = 0.f;
            for (int e = beg + lane; e < end; e += 64) {
                float ex = expf(attn_spill[e] - m);
                attn_spill[e] = ex;
                z += ex;
            }
#pragma unroll
            for (int off = 32; off; off >>= 1) z += __shfl_xor(z, off);
            float rz = 1.f / z;
            for (int e = beg + lane; e < end; e += 64) attn_spill[e] *= rz;
        }
    }

    // ---- aggregation: 16 lanes/edge, up to 16 edges in flight per wave ----
    int sub = lane >> 4;          // 0..3
    int cl = lane & 15;
    const _Float16* hbase = h + cl * HPL;
    f16x8 acc[NV] = {};

    if (small) {
        int k = sub;
        for (; k + 12 < deg; k += 16) {
            float2 wd0 = wdbuf[wv][k];
            float2 wd1 = wdbuf[wv][k + 4];
            float2 wd2 = wdbuf[wv][k + 8];
            float2 wd3 = wdbuf[wv][k + 12];
            const _Float16* p0 = hbase + ((unsigned)__float_as_int(wd0.y) * D);
            const _Float16* p1 = hbase + ((unsigned)__float_as_int(wd1.y) * D);
            const _Float16* p2 = hbase + ((unsigned)__float_as_int(wd2.y) * D);
            const _Float16* p3 = hbase + ((unsigned)__float_as_int(wd3.y) * D);
            f16x8 v0[NV], v1[NV], v2[NV], v3[NV];
#pragma unroll
            for (int q = 0; q < NV; ++q) v0[q] = *(const f16x8*)(p0 + q * 8);
#pragma unroll
            for (int q = 0; q < NV; ++q) v1[q] = *(const f16x8*)(p1 + q * 8);
#pragma unroll
            for (int q = 0; q < NV; ++q) v2[q] = *(const f16x8*)(p2 + q * 8);
#pragma unroll
            for (int q = 0; q < NV; ++q) v3[q] = *(const f16x8*)(p3 + q * 8);
            _Float16 w0 = (_Float16)wd0.x, w1 = (_Float16)wd1.x;
            _Float16 w2 = (_Float16)wd2.x, w3 = (_Float16)wd3.x;
            f16x8 a0 = {w0, w0, w0, w0, w0, w0, w0, w0};
            f16x8 a1 = {w1, w1, w1, w1, w1, w1, w1, w1};
            f16x8 a2 = {w2, w2, w2, w2, w2, w2, w2, w2};
            f16x8 a3 = {w3, w3, w3, w3, w3, w3, w3, w3};
#pragma unroll
            for (int q = 0; q < NV; ++q) acc[q] += v0[q] * a0;
#pragma unroll
            for (int q = 0; q < NV; ++q) acc[q] += v1[q] * a1;
#pragma unroll
            for (int q = 0; q < NV; ++q) acc[q] += v2[q] * a2;
#pragma unroll
            for (int q = 0; q < NV; ++q) acc[q] += v3[q] * a3;
        }
        for (; k < deg; k += 4) {
            float2 wd = wdbuf[wv][k];
            const _Float16* hp = hbase + ((unsigned)__float_as_int(wd.y) * D);
            f16x8 vv[NV];
#pragma unroll
            for (int q = 0; q < NV; ++q) vv[q] = *(const f16x8*)(hp + q * 8);
            _Float16 wh = (_Float16)wd.x;
            f16x8 a8 = {wh, wh, wh, wh, wh, wh, wh, wh};
#pragma unroll
            for (int q = 0; q < NV; ++q) acc[q] += vv[q] * a8;
        }
    } else {
        for (int k = sub; k < deg; k += 4) {
            float a = attn_spill[beg + k];
            int d = csr_dst[beg + k];
            const _Float16* hp = hbase + ((unsigned)d * D);
            f16x8 vv[NV];
#pragma unroll
            for (int q = 0; q < NV; ++q) vv[q] = *(const f16x8*)(hp + q * 8);
            _Float16 wh = (_Float16)a;
            f16x8 a8 = {wh, wh, wh, wh, wh, wh, wh, wh};
#pragma unroll
            for (int q = 0; q < NV; ++q) acc[q] += vv[q] * a8;
        }
    }

    // packed reduce across the 4 sub-groups (lanes differing in bits 4,5)
    union { f16x8 v; unsigned w[4]; } A[NV];
#pragma unroll
    for (int q = 0; q < NV; ++q) A[q].v = acc[q];
#pragma unroll
    for (int q = 0; q < NV; ++q)
#pragma unroll
        for (int i = 0; i < 4; ++i) {
            unsigned u = A[q].w[i];
            u = pkadd(u, (unsigned)__shfl_xor((int)u, 16));
            u = pkadd(u, (unsigned)__shfl_xor((int)u, 32));
            A[q].w[i] = u;
        }
    if (sub == 0) {
        _Float16* op = out + (size_t)row * D + cl * HPL;
#pragma unroll
        for (int q = 0; q < NV; ++q) {
            f16x8 o;
#pragma unroll
            for (int j = 0; j < 8; ++j) o[j] = (_Float16)eluf((float)A[q].v[j]);
            *(f16x8*)(op + q * 8) = o;
        }
    }
}

// ---------------------------------------------------------------------------
// final: logits = h1 @ lin_w + lin_b ; log_softmax; one wave per row
// ---------------------------------------------------------------------------
__global__ __launch_bounds__(256) void final16_kernel(const _Float16* __restrict__ h, // [N,128]
                                                      const float* __restrict__ lw,   // [128,40]
                                                      const float* __restrict__ lb,   // [40]
                                                      float* __restrict__ out, int nrows)
{
    __shared__ __align__(16) float rowbuf[4][128];
    int lane = threadIdx.x & 63;
    int wv = threadIdx.x >> 6;
    int row = blockIdx.x * 4 + wv;
    bool active = row < nrows;
    if (active) {
        f16x2 v = *(const f16x2*)&h[(size_t)row * 128 + lane * 2];
        rowbuf[wv][lane * 2] = (float)v[0];
        rowbuf[wv][lane * 2 + 1] = (float)v[1];
    }
    __syncthreads();
    float logit = 0.f;
    if (active && lane < 40) {
        float s = lb[lane];
        for (int k = 0; k < 128; ++k) s += rowbuf[wv][k] * lw[k * 40 + lane];
        logit = s;
    }
    float v = (active && lane < 40) ? logit : -INFINITY;
#pragma unroll
    for (int off = 32; off; off >>= 1) v = fmaxf(v, __shfl_xor(v, off));
    float ex = (active && lane < 40) ? expf(logit - v) : 0.f;
    float zs = ex;
#pragma unroll
    for (int off = 32; off; off >>= 1) zs += __shfl_xor(zs, off);
    if (active && lane < 40) out[(size_t)row * 40 + lane] = logit - v - logf(zs);
}

// ---------------------------------------------------------------------------
extern "C" void kernel_launch(void* const* d_in, const int* in_sizes, int n_in,
                              void* d_out, int out_size, void* d_ws, size_t ws_size,
                              hipStream_t stream)
{
    const float* x   = (const float*)d_in[0];   // [N,256]
    const int*  edge = (const int*)d_in[1];     // [2,E]
    const float* W0  = (const float*)d_in[2];   // [256,256]
    const float* a0  = (const float*)d_in[3];   // [512,1]
    const float* W1  = (const float*)d_in[4];   // [256,128]
    const float* a1  = (const float*)d_in[5];   // [256,1]
    const float* lw  = (const float*)d_in[6];   // [128,40]
    const float* lb  = (const float*)d_in[7];   // [40]
    float* out = (float*)d_out;

    const int N = in_sizes[0] / 256;
    const int E = in_sizes[1] / 2;
    const int* src = edge;
    const int* dst = edge + E;

    // ---- workspace layout ----
    _Float16* bufA = (_Float16*)d_ws;                 // N*256 halves (h0, then h1)
    _Float16* bufB = bufA + (size_t)N * 256;          // N*256 halves (h0', then h1')
    _Float16* W0t  = bufB + (size_t)N * 256;          // 256*256
    _Float16* W1t  = W0t + 256 * 256;                 // 128*256
    float* ssrc = (float*)(W1t + 128 * 256);          // N
    float* sdst = ssrc + N;                            // N
    float* attn = sdst + N;                            // E (spill for deg>128 rows)
    int* rowptr  = (int*)(attn + E);                   // N+1
    int* cnt     = rowptr + (N + 1);                   // N
    int* csr_dst = cnt + N;                            // E
    int* bsum    = csr_dst + E;                        // 128
    int* bhist   = bsum + 128;                         // 256
    int* bbase   = bhist + 256;                        // 257
    int* gcur    = bbase + 257;                        // 256
    // pairs aliases bufA: only live before gemm-0 writes bufA (stream-ordered)
    int* pairs   = (int*)bufA;                         // E ints (packed lrow|dst)

    const int rowBlocks = (N + 3) / 4;
    const int nb = (N + 1023) / 1024;                  // scan chunks (<=128)
    const int NB = (N + BIN_ROWS - 1) >> BIN_SHIFT;    // buckets (<=256)
    const int blocksE = (E + 4095) / 4096;
    const int gemmBlocks = (N + GBM - 1) / GBM;

    // ---- CSR build (bucketed, packed) ----
    hipMemsetAsync(bhist, 0, 256 * sizeof(int), stream);
    bucket_count_kernel<<<blocksE, 256, 0, stream>>>(src, bhist, E);
    bucket_scan_kernel<<<1, 256, 0, stream>>>(bhist, bbase, gcur, E);
    pass1_bin_kernel<<<blocksE, 256, 0, stream>>>(src, dst, gcur, pairs, E);
    row_count_kernel<<<NB, 256, 0, stream>>>(pairs, bbase, cnt, N);
    bsum_kernel<<<nb, 256, 0, stream>>>(cnt, bsum, N);
    bscan_kernel<<<1, 128, 0, stream>>>(bsum, nb, rowptr, N);
    chunkscan_kernel<<<nb, 256, 0, stream>>>(cnt, bsum, rowptr, N);
    pass2_scatter_kernel<<<NB, 256, 0, stream>>>(pairs, bbase, rowptr, csr_dst, N);

    // ---- weight transposes (fp16) ----
    transpose16_kernel<<<(256 * 256 + 255) / 256, 256, 0, stream>>>(W0, W0t, 256, 256);
    transpose16_kernel<<<(128 * 256 + 255) / 256, 256, 0, stream>>>(W1, W1t, 256, 128);

    // ---- layer 0: d = 256 (A = x fp32, cvt in staging; s fused in epilogue) ----
    hipMemsetAsync(ssrc, 0, (size_t)2 * N * sizeof(float), stream);
    gemm16_kernel<true, true, 256><<<gemmBlocks, 256, 0, stream>>>(
        x, W0t, bufA, N, 256, a0, 256, ssrc, sdst);
    attnagg_kernel<256><<<rowBlocks, 256, 0, stream>>>(bufA, ssrc, sdst, csr_dst, rowptr, attn, bufB, N);

    // ---- layer 1: d = 128 ----
    hipMemsetAsync(ssrc, 0, (size_t)2 * N * sizeof(float), stream);
    gemm16_kernel<false, true, 128><<<gemmBlocks, 256, 0, stream>>>(
        bufB, W1t, bufA, N, 256, a1, 128, ssrc, sdst);
    attnagg_kernel<128><<<rowBlocks, 256, 0, stream>>>(bufA, ssrc, sdst, csr_dst, rowptr, attn, bufB, N);

    // ---- final linear + log_softmax ----
    final16_kernel<<<rowBlocks, 256, 0, stream>>>(bufB, lw, lb, out, N);
}

// Round 9
// 616.252 us; speedup vs baseline: 1.1260x; 1.0508x over previous
//
#include <hip/hip_runtime.h>
#include <cstddef>
#include <cstdint>

#define LRELU_ALPHA 0.2f
#define BIN_SHIFT 9
#define BIN_ROWS  (1 << BIN_SHIFT)   // 512 rows per bucket
// packed pair: (local_row << 17) | dst  -- requires N <= 131072 (N = 100000)
#define DST_BITS 17
#define DST_MASK ((1 << DST_BITS) - 1)

typedef _Float16 f16x8 __attribute__((ext_vector_type(8)));
typedef _Float16 f16x4 __attribute__((ext_vector_type(4)));
typedef _Float16 f16x2 __attribute__((ext_vector_type(2)));
typedef float    f32x4 __attribute__((ext_vector_type(4)));

// ---------------------------------------------------------------------------
// prep: W transposes to fp16 + zero bhist (one kernel)
// ---------------------------------------------------------------------------
__global__ __launch_bounds__(256) void prep_kernel(const float* __restrict__ W0,
                                                   const float* __restrict__ W1,
                                                   _Float16* __restrict__ W0t,
                                                   _Float16* __restrict__ W1t,
                                                   int* __restrict__ bhist)
{
    int i = blockIdx.x * 256 + threadIdx.x;
    if (i < 65536) {
        int n = i >> 8, k = i & 255;
        W0t[i] = (_Float16)W0[k * 256 + n];
    } else if (i < 98304) {
        int j = i - 65536;
        int n = j >> 8, k = j & 255;
        W1t[j] = (_Float16)W1[k * 128 + n];
    } else if (i < 98304 + 256) {
        bhist[i - 98304] = 0;
    }
}

// ---------------------------------------------------------------------------
// CSR build, locality-bucketed, packed pairs
// ---------------------------------------------------------------------------
__global__ __launch_bounds__(256) void bucket_count_kernel(const int* __restrict__ src,
                                                           int* __restrict__ bhist, int E)
{
    __shared__ int hist[256];
    int t = threadIdx.x;
    hist[t] = 0;
    __syncthreads();
    int base = blockIdx.x * 4096;
#pragma unroll
    for (int j = 0; j < 16; ++j) {
        int i = base + j * 256 + t;
        if (i < E) atomicAdd(&hist[src[i] >> BIN_SHIFT], 1);
    }
    __syncthreads();
    if (hist[t]) atomicAdd(&bhist[t], hist[t]);
}

__global__ __launch_bounds__(256) void bucket_scan_kernel(const int* __restrict__ bhist,
                                                          int* __restrict__ bbase,
                                                          int* __restrict__ gcur, int E)
{
    __shared__ int buf[256];
    int t = threadIdx.x;
    int v = bhist[t];
    buf[t] = v;
    __syncthreads();
    for (int off = 1; off < 256; off <<= 1) {
        int u = (t >= off) ? buf[t - off] : 0;
        __syncthreads();
        buf[t] += u;
        __syncthreads();
    }
    int excl = buf[t] - v;
    bbase[t] = excl;
    gcur[t] = excl;
    if (t == 255) bbase[256] = buf[255];
}

// bin packed (lrow|dst) into bucket-contiguous order
__global__ __launch_bounds__(256) void pass1_bin_kernel(const int* __restrict__ src,
                                                        const int* __restrict__ dst,
                                                        int* __restrict__ gcur,
                                                        int* __restrict__ pairs, int E)
{
    __shared__ int hist[256];
    __shared__ int cur[256];
    int t = threadIdx.x;
    hist[t] = 0;
    __syncthreads();
    int base = blockIdx.x * 4096;
    int s_[16], d_[16];
#pragma unroll
    for (int j = 0; j < 16; ++j) {
        int i = base + j * 256 + t;
        if (i < E) {
            s_[j] = src[i];
            d_[j] = dst[i];
            atomicAdd(&hist[s_[j] >> BIN_SHIFT], 1);
        } else s_[j] = -1;
    }
    __syncthreads();
    cur[t] = atomicAdd(&gcur[t], hist[t]);
    __syncthreads();
#pragma unroll
    for (int j = 0; j < 16; ++j) {
        if (s_[j] >= 0) {
            int pos = atomicAdd(&cur[s_[j] >> BIN_SHIFT], 1);
            pairs[pos] = ((s_[j] & (BIN_ROWS - 1)) << DST_BITS) | d_[j];
        }
    }
}

// one block per bucket: per-row counts in LDS + in-block scan -> rowptr direct
__global__ __launch_bounds__(256) void rowptr_kernel(const int* __restrict__ pairs,
                                                     const int* __restrict__ bbase,
                                                     int* __restrict__ rowptr,
                                                     int N, int E)
{
    __shared__ int c[BIN_ROWS];
    __shared__ int tsum[256];
    int b = blockIdx.x, t = threadIdx.x;
    int rowbase = b << BIN_SHIFT;
    int nrows = min(BIN_ROWS, N - rowbase);
    c[t] = 0; c[t + 256] = 0;
    __syncthreads();
    int beg = bbase[b], end = bbase[b + 1];
    for (int i = beg + t; i < end; i += 256)
        atomicAdd(&c[pairs[i] >> DST_BITS], 1);
    __syncthreads();
    int c0 = c[2 * t], c1 = c[2 * t + 1];
    int s = c0 + c1;
    tsum[t] = s;
    __syncthreads();
    for (int off = 1; off < 256; off <<= 1) {
        int u = (t >= off) ? tsum[t - off] : 0;
        __syncthreads();
        tsum[t] += u;
        __syncthreads();
    }
    int excl = beg + tsum[t] - s;
    if (2 * t < nrows)     rowptr[rowbase + 2 * t] = excl;
    if (2 * t + 1 < nrows) rowptr[rowbase + 2 * t + 1] = excl + c0;
    if (b == (int)gridDim.x - 1 && t == 0) rowptr[N] = E;
}

__global__ __launch_bounds__(256) void pass2_scatter_kernel(const int* __restrict__ pairs,
                                                            const int* __restrict__ bbase,
                                                            const int* __restrict__ rowptr,
                                                            int* __restrict__ csr_dst, int N)
{
    __shared__ int cur[BIN_ROWS];
    int b = blockIdx.x, t = threadIdx.x;
    int rowbase = b << BIN_SHIFT;
    int nrows = min(BIN_ROWS, N - rowbase);
    if (t < nrows) cur[t] = rowptr[rowbase + t];
    if (t + 256 < nrows) cur[t + 256] = rowptr[rowbase + t + 256];
    __syncthreads();
    int beg = bbase[b], end = bbase[b + 1];
    for (int i = beg + t; i < end; i += 256) {
        int p = pairs[i];
        int pos = atomicAdd(&cur[p >> DST_BITS], 1);
        csr_dst[pos] = p & DST_MASK;
    }
}

// ---------------------------------------------------------------------------
// MFMA f16 GEMM v3: one block-column covers ALL Nw columns (GBN = Nw), A
// streamed once.  Double-buffered LDS, global loads issued before MFMA,
// ONE barrier per k-step.
// FUSE_S: each wave's 64-col slice gives a PARTIAL row dot; partials are
// reduced across the 4 waves via LDS (spart) then stored plainly.
// (R8 bug: plain per-wave stores dropped 3/4 of the dot.)
// ---------------------------------------------------------------------------
#define GBM 64
#define GBK 32
#define LDP 40

template <bool CVTA, bool FUSE_S, int GBN>
__global__ __launch_bounds__(256) void gemm16_kernel(const void* __restrict__ Ap,
                                                     const _Float16* __restrict__ Bt,
                                                     _Float16* __restrict__ C,
                                                     int M, int K,
                                                     const float* __restrict__ avec,
                                                     int aoff,
                                                     float* __restrict__ ssrc,
                                                     float* __restrict__ sdst)
{
    constexpr int NT = GBN / 64;          // n-frags per wave; also B vecs per thread
    __shared__ __align__(16) _Float16 Ash[2][GBM * LDP];
    __shared__ __align__(16) _Float16 Bsh[2][GBN * LDP];
    __shared__ float2 spart[4][GBM];      // per-wave partial (ps,pd) per local row
    const int tid = threadIdx.x;
    const int lane = tid & 63;
    const int w = tid >> 6;               // 0..3
    const int m0 = blockIdx.x * GBM;
    const int l15 = lane & 15;
    const int kq = lane >> 4;
    const int sr = tid >> 2;              // 0..63
    const int sc = tid & 3;
    const int wc = w * (GBN / 4);         // wave col base
    const int gmS = m0 + sr;

    f16x8 va, vb[NT];
    auto loadT = [&](int k0, f16x8& a, f16x8* b) {
        a = f16x8{};
        if (gmS < M) {
            if constexpr (CVTA) {
                const float* Af = (const float*)Ap;
                float4 u0 = *(const float4*)(Af + (size_t)gmS * K + k0 + sc * 8);
                float4 u1 = *(const float4*)(Af + (size_t)gmS * K + k0 + sc * 8 + 4);
                a[0] = (_Float16)u0.x; a[1] = (_Float16)u0.y;
                a[2] = (_Float16)u0.z; a[3] = (_Float16)u0.w;
                a[4] = (_Float16)u1.x; a[5] = (_Float16)u1.y;
                a[6] = (_Float16)u1.z; a[7] = (_Float16)u1.w;
            } else {
                a = *(const f16x8*)((const _Float16*)Ap + (size_t)gmS * K + k0 + sc * 8);
            }
        }
#pragma unroll
        for (int it = 0; it < NT; ++it)
            b[it] = *(const f16x8*)(Bt + (size_t)(sr + it * 64) * K + k0 + sc * 8);
    };
    auto storeT = [&](int buf, const f16x8& a, const f16x8* b) {
        *(f16x8*)&Ash[buf][sr * LDP + sc * 8] = a;
#pragma unroll
        for (int it = 0; it < NT; ++it)
            *(f16x8*)&Bsh[buf][(sr + it * 64) * LDP + sc * 8] = b[it];
    };

    loadT(0, va, vb);
    storeT(0, va, vb);
    __syncthreads();

    f32x4 acc[4][NT] = {};
    int cur = 0;
    for (int k0 = 0; k0 < K; k0 += GBK) {
        bool nxt = (k0 + GBK) < K;
        f16x8 na, nb[NT];
        if (nxt) loadT(k0 + GBK, na, nb);     // issue early; hides under MFMA

        f16x8 af[4], bf[NT];
#pragma unroll
        for (int mt = 0; mt < 4; ++mt)
            af[mt] = *(const f16x8*)&Ash[cur][(mt * 16 + l15) * LDP + kq * 8];
#pragma unroll
        for (int nt = 0; nt < NT; ++nt)
            bf[nt] = *(const f16x8*)&Bsh[cur][(wc + nt * 16 + l15) * LDP + kq * 8];
#pragma unroll
        for (int mt = 0; mt < 4; ++mt)
#pragma unroll
            for (int nt = 0; nt < NT; ++nt)
                acc[mt][nt] = __builtin_amdgcn_mfma_f32_16x16x32_f16(af[mt], bf[nt],
                                                                     acc[mt][nt], 0, 0, 0);
        if (nxt) storeT(cur ^ 1, na, nb);
        __syncthreads();
        cur ^= 1;
    }

#pragma unroll
    for (int mt = 0; mt < 4; ++mt) {
#pragma unroll
        for (int r = 0; r < 4; ++r) {
            int gm = m0 + mt * 16 + kq * 4 + r;
            if (gm < M) {
#pragma unroll
                for (int nt = 0; nt < NT; ++nt)
                    C[(size_t)gm * GBN + wc + nt * 16 + l15] = (_Float16)acc[mt][nt][r];
            }
        }
    }

    if constexpr (FUSE_S) {
        float as[NT], ad[NT];
#pragma unroll
        for (int nt = 0; nt < NT; ++nt) {
            int c = wc + nt * 16 + l15;
            as[nt] = avec[c];
            ad[nt] = avec[aoff + c];
        }
#pragma unroll
        for (int mt = 0; mt < 4; ++mt) {
#pragma unroll
            for (int r = 0; r < 4; ++r) {
                float ps = 0.f, pd = 0.f;
#pragma unroll
                for (int nt = 0; nt < NT; ++nt) {
                    float v = acc[mt][nt][r];
                    ps += v * as[nt];
                    pd += v * ad[nt];
                }
#pragma unroll
                for (int off = 1; off < 16; off <<= 1) {
                    ps += __shfl_xor(ps, off);
                    pd += __shfl_xor(pd, off);
                }
                int lr = mt * 16 + kq * 4 + r;       // local row 0..63
                if (l15 == 0) spart[w][lr] = make_float2(ps, pd);
            }
        }
        __syncthreads();
        if (tid < GBM) {
            float2 p0 = spart[0][tid], p1 = spart[1][tid];
            float2 p2 = spart[2][tid], p3 = spart[3][tid];
            int gm = m0 + tid;
            if (gm < M) {
                ssrc[gm] = p0.x + p1.x + p2.x + p3.x;
                sdst[gm] = p0.y + p1.y + p2.y + p3.y;
            }
        }
    }
}

// ---------------------------------------------------------------------------
// FUSED per-row softmax + aggregation + ELU (+ optional final linear +
// log_softmax for the last layer).
// One wave per row; 16 lanes/edge; 4-edge-deep gather pipeline; packed f16
// FMA accumulate.  deg<=128: weights+dst in per-wave LDS.  deg>128: spill.
// ---------------------------------------------------------------------------
__device__ __forceinline__ float eluf(float x) { return x > 0.f ? x : expm1f(x); }

union h2u { f16x2 h; unsigned u; };
__device__ __forceinline__ unsigned pkadd(unsigned a, unsigned b)
{
    h2u x, y; x.u = a; y.u = b; x.h += y.h; return x.u;
}

template <int D, bool FUSE_FINAL>
__global__ __launch_bounds__(256) void attnagg_kernel(const _Float16* __restrict__ h,
                                                      const float* __restrict__ ssrc,
                                                      const float* __restrict__ sdst,
                                                      const int* __restrict__ csr_dst,
                                                      const int* __restrict__ rowptr,
                                                      float* __restrict__ attn_spill,
                                                      _Float16* __restrict__ out16,
                                                      const float* __restrict__ lw,
                                                      const float* __restrict__ lb,
                                                      float* __restrict__ outf, int nrows)
{
    constexpr int HPL = D / 16;            // halves per lane: 16 (D=256) or 8 (D=128)
    constexpr int NV = HPL / 8;            // f16x8 vectors per lane: 2 or 1
    __shared__ float2 wdbuf[4][128];
    __shared__ float rowbuf[FUSE_FINAL ? 4 : 1][128];
    int lane = threadIdx.x & 63;
    int wv = threadIdx.x >> 6;
    int row = blockIdx.x * 4 + wv;
    if (row >= nrows) return;
    int beg = rowptr[row], end = rowptr[row + 1];
    int deg = end - beg;
    bool small = (deg <= 128);

    if (deg > 0) {
        float ss = ssrc[row];
        if (small) {
            int e0 = beg + lane, e1 = e0 + 64;
            int d0 = 0, d1 = 0;
            float sc0 = -INFINITY, sc1 = -INFINITY;
            if (e0 < end) {
                d0 = csr_dst[e0];
                float sc = ss + sdst[d0];
                sc0 = (sc > 0.f) ? sc : LRELU_ALPHA * sc;
            }
            if (e1 < end) {
                d1 = csr_dst[e1];
                float sc = ss + sdst[d1];
                sc1 = (sc > 0.f) ? sc : LRELU_ALPHA * sc;
            }
            float m = fmaxf(sc0, sc1);
#pragma unroll
            for (int off = 32; off; off >>= 1) m = fmaxf(m, __shfl_xor(m, off));
            float ex0 = (e0 < end) ? expf(sc0 - m) : 0.f;
            float ex1 = (e1 < end) ? expf(sc1 - m) : 0.f;
            float z = ex0 + ex1;
#pragma unroll
            for (int off = 32; off; off >>= 1) z += __shfl_xor(z, off);
            float rz = 1.f / z;
            if (e0 < end) wdbuf[wv][lane] = make_float2(ex0 * rz, __int_as_float(d0));
            if (e1 < end) wdbuf[wv][64 + lane] = make_float2(ex1 * rz, __int_as_float(d1));
        } else {
            float m = -INFINITY;
            for (int e = beg + lane; e < end; e += 64) {
                float sc = ss + sdst[csr_dst[e]];
                sc = (sc > 0.f) ? sc : LRELU_ALPHA * sc;
                attn_spill[e] = sc;
                m = fmaxf(m, sc);
            }
#pragma unroll
            for (int off = 32; off; off >>= 1) m = fmaxf(m, __shfl_xor(m, off));
            float z = 0.f;
            for (int e = beg + lane; e < end; e += 64) {
                float ex = expf(attn_spill[e] - m);
                attn_spill[e] = ex;
                z += ex;
            }
#pragma unroll
            for (int off = 32; off; off >>= 1) z += __shfl_xor(z, off);
            float rz = 1.f / z;
            for (int e = beg + lane; e < end; e += 64) attn_spill[e] *= rz;
        }
    }

    // ---- aggregation: 16 lanes/edge, 4-edge-deep pipeline ----
    int sub = lane >> 4;          // 0..3
    int cl = lane & 15;
    const _Float16* hbase = h + cl * HPL;
    f16x8 acc[NV] = {};

    if (small) {
        int k = sub;
        for (; k + 12 < deg; k += 16) {
            float2 wd0 = wdbuf[wv][k];
            float2 wd1 = wdbuf[wv][k + 4];
            float2 wd2 = wdbuf[wv][k + 8];
            float2 wd3 = wdbuf[wv][k + 12];
            const _Float16* p0 = hbase + ((unsigned)__float_as_int(wd0.y) * D);
            const _Float16* p1 = hbase + ((unsigned)__float_as_int(wd1.y) * D);
            const _Float16* p2 = hbase + ((unsigned)__float_as_int(wd2.y) * D);
            const _Float16* p3 = hbase + ((unsigned)__float_as_int(wd3.y) * D);
            f16x8 v0[NV], v1[NV], v2[NV], v3[NV];
#pragma unroll
            for (int q = 0; q < NV; ++q) v0[q] = *(const f16x8*)(p0 + q * 8);
#pragma unroll
            for (int q = 0; q < NV; ++q) v1[q] = *(const f16x8*)(p1 + q * 8);
#pragma unroll
            for (int q = 0; q < NV; ++q) v2[q] = *(const f16x8*)(p2 + q * 8);
#pragma unroll
            for (int q = 0; q < NV; ++q) v3[q] = *(const f16x8*)(p3 + q * 8);
            _Float16 w0 = (_Float16)wd0.x, w1 = (_Float16)wd1.x;
            _Float16 w2 = (_Float16)wd2.x, w3 = (_Float16)wd3.x;
            f16x8 a0 = {w0, w0, w0, w0, w0, w0, w0, w0};
            f16x8 a1 = {w1, w1, w1, w1, w1, w1, w1, w1};
            f16x8 a2 = {w2, w2, w2, w2, w2, w2, w2, w2};
            f16x8 a3 = {w3, w3, w3, w3, w3, w3, w3, w3};
#pragma unroll
            for (int q = 0; q < NV; ++q) acc[q] += v0[q] * a0;
#pragma unroll
            for (int q = 0; q < NV; ++q) acc[q] += v1[q] * a1;
#pragma unroll
            for (int q = 0; q < NV; ++q) acc[q] += v2[q] * a2;
#pragma unroll
            for (int q = 0; q < NV; ++q) acc[q] += v3[q] * a3;
        }
        for (; k < deg; k += 4) {
            float2 wd = wdbuf[wv][k];
            const _Float16* hp = hbase + ((unsigned)__float_as_int(wd.y) * D);
            f16x8 vv[NV];
#pragma unroll
            for (int q = 0; q < NV; ++q) vv[q] = *(const f16x8*)(hp + q * 8);
            _Float16 wh = (_Float16)wd.x;
            f16x8 a8 = {wh, wh, wh, wh, wh, wh, wh, wh};
#pragma unroll
            for (int q = 0; q < NV; ++q) acc[q] += vv[q] * a8;
        }
    } else {
        for (int k = sub; k < deg; k += 4) {
            float a = attn_spill[beg + k];
            int d = csr_dst[beg + k];
            const _Float16* hp = hbase + ((unsigned)d * D);
            f16x8 vv[NV];
#pragma unroll
            for (int q = 0; q < NV; ++q) vv[q] = *(const f16x8*)(hp + q * 8);
            _Float16 wh = (_Float16)a;
            f16x8 a8 = {wh, wh, wh, wh, wh, wh, wh, wh};
#pragma unroll
            for (int q = 0; q < NV; ++q) acc[q] += vv[q] * a8;
        }
    }

    // packed reduce across the 4 sub-groups
    union { f16x8 v; unsigned w[4]; } A[NV];
#pragma unroll
    for (int q = 0; q < NV; ++q) A[q].v = acc[q];
#pragma unroll
    for (int q = 0; q < NV; ++q)
#pragma unroll
        for (int i = 0; i < 4; ++i) {
            unsigned u = A[q].w[i];
            u = pkadd(u, (unsigned)__shfl_xor((int)u, 16));
            u = pkadd(u, (unsigned)__shfl_xor((int)u, 32));
            A[q].w[i] = u;
        }

    if constexpr (!FUSE_FINAL) {
        if (sub == 0) {
            _Float16* op = out16 + (size_t)row * D + cl * HPL;
#pragma unroll
            for (int q = 0; q < NV; ++q) {
                f16x8 o;
#pragma unroll
                for (int j = 0; j < 8; ++j) o[j] = (_Float16)eluf((float)A[q].v[j]);
                *(f16x8*)(op + q * 8) = o;
            }
        }
    } else {
        // D == 128: row (after ELU) -> per-wave LDS, then logits + log_softmax
        if (sub == 0) {
#pragma unroll
            for (int j = 0; j < 8; ++j)
                rowbuf[wv][cl * 8 + j] = eluf((float)A[0].v[j]);
        }
        __builtin_amdgcn_wave_barrier();   // sched fence; in-order DS pipe per wave
        float logit = 0.f;
        if (lane < 40) {
            float s = lb[lane];
#pragma unroll 4
            for (int k = 0; k < 128; ++k) s += rowbuf[wv][k] * lw[k * 40 + lane];
            logit = s;
        }
        float v = (lane < 40) ? logit : -INFINITY;
#pragma unroll
        for (int off = 32; off; off >>= 1) v = fmaxf(v, __shfl_xor(v, off));
        float ex = (lane < 40) ? expf(logit - v) : 0.f;
        float zs = ex;
#pragma unroll
        for (int off = 32; off; off >>= 1) zs += __shfl_xor(zs, off);
        if (lane < 40) outf[(size_t)row * 40 + lane] = logit - v - logf(zs);
    }
}

// ---------------------------------------------------------------------------
extern "C" void kernel_launch(void* const* d_in, const int* in_sizes, int n_in,
                              void* d_out, int out_size, void* d_ws, size_t ws_size,
                              hipStream_t stream)
{
    const float* x   = (const float*)d_in[0];   // [N,256]
    const int*  edge = (const int*)d_in[1];     // [2,E]
    const float* W0  = (const float*)d_in[2];   // [256,256]
    const float* a0  = (const float*)d_in[3];   // [512,1]
    const float* W1  = (const float*)d_in[4];   // [256,128]
    const float* a1  = (const float*)d_in[5];   // [256,1]
    const float* lw  = (const float*)d_in[6];   // [128,40]
    const float* lb  = (const float*)d_in[7];   // [40]
    float* out = (float*)d_out;

    const int N = in_sizes[0] / 256;
    const int E = in_sizes[1] / 2;
    const int* src = edge;
    const int* dst = edge + E;

    // ---- workspace layout ----
    _Float16* bufA = (_Float16*)d_ws;                 // N*256 halves (h0, then h1)
    _Float16* bufB = bufA + (size_t)N * 256;          // N*256 halves (h0')
    _Float16* W0t  = bufB + (size_t)N * 256;          // 256*256
    _Float16* W1t  = W0t + 256 * 256;                 // 128*256
    float* ssrc = (float*)(W1t + 128 * 256);          // N
    float* sdst = ssrc + N;                            // N
    float* attn = sdst + N;                            // E (spill for deg>128 rows)
    int* rowptr  = (int*)(attn + E);                   // N+1
    int* csr_dst = rowptr + (N + 1);                   // E
    int* bhist   = csr_dst + E;                        // 256
    int* bbase   = bhist + 256;                        // 257
    int* gcur    = bbase + 257;                        // 256
    // pairs aliases bufA: dead before gemm-0 writes bufA (stream-ordered)
    int* pairs   = (int*)bufA;                         // E ints (packed lrow|dst)

    const int rowBlocks = (N + 3) / 4;
    const int NB = (N + BIN_ROWS - 1) >> BIN_SHIFT;    // buckets (<=256)
    const int blocksE = (E + 4095) / 4096;
    const int gemmBlocks = (N + GBM - 1) / GBM;

    // ---- prep (transposes + bhist zero) ----
    prep_kernel<<<385, 256, 0, stream>>>(W0, W1, W0t, W1t, bhist);

    // ---- CSR build (bucketed, packed) ----
    bucket_count_kernel<<<blocksE, 256, 0, stream>>>(src, bhist, E);
    bucket_scan_kernel<<<1, 256, 0, stream>>>(bhist, bbase, gcur, E);
    pass1_bin_kernel<<<blocksE, 256, 0, stream>>>(src, dst, gcur, pairs, E);
    rowptr_kernel<<<NB, 256, 0, stream>>>(pairs, bbase, rowptr, N, E);
    pass2_scatter_kernel<<<NB, 256, 0, stream>>>(pairs, bbase, rowptr, csr_dst, N);

    // ---- layer 0: d = 256 ----
    gemm16_kernel<true, true, 256><<<gemmBlocks, 256, 0, stream>>>(
        x, W0t, bufA, N, 256, a0, 256, ssrc, sdst);
    attnagg_kernel<256, false><<<rowBlocks, 256, 0, stream>>>(
        bufA, ssrc, sdst, csr_dst, rowptr, attn, bufB, nullptr, nullptr, nullptr, N);

    // ---- layer 1: d = 128 (final linear + log_softmax fused) ----
    gemm16_kernel<false, true, 128><<<gemmBlocks, 256, 0, stream>>>(
        bufB, W1t, bufA, N, 256, a1, 128, ssrc, sdst);
    attnagg_kernel<128, true><<<rowBlocks, 256, 0, stream>>>(
        bufA, ssrc, sdst, csr_dst, rowptr, attn, nullptr, lw, lb, out, N);
}

// Round 10
// 527.134 us; speedup vs baseline: 1.3164x; 1.1691x over previous
//
#include <hip/hip_runtime.h>
#include <cstddef>
#include <cstdint>

#define LRELU_ALPHA 0.2f
#define BIN_SHIFT 9
#define BIN_ROWS  (1 << BIN_SHIFT)   // 512 rows per bucket
#define BUCKET_CAP 18432             // mean 16327, std ~128 -> +16 sigma margin
// packed pair: (local_row << 17) | dst  -- requires N <= 131072 (N = 100000)
#define DST_BITS 17
#define DST_MASK ((1 << DST_BITS) - 1)

typedef _Float16 f16x8 __attribute__((ext_vector_type(8)));
typedef _Float16 f16x4 __attribute__((ext_vector_type(4)));
typedef _Float16 f16x2 __attribute__((ext_vector_type(2)));
typedef float    f32x4 __attribute__((ext_vector_type(4)));

// ---------------------------------------------------------------------------
// prep: W transposes to fp16, pack lw into f16x2 pairs, zero gcur
// ---------------------------------------------------------------------------
__global__ __launch_bounds__(256) void prep_kernel(const float* __restrict__ W0,
                                                   const float* __restrict__ W1,
                                                   const float* __restrict__ lw,
                                                   _Float16* __restrict__ W0t,
                                                   _Float16* __restrict__ W1t,
                                                   f16x2* __restrict__ lwp,
                                                   int* __restrict__ gcur)
{
    int i = blockIdx.x * 256 + threadIdx.x;
    if (i < 65536) {
        int n = i >> 8, k = i & 255;
        W0t[i] = (_Float16)W0[k * 256 + n];
    } else if (i < 98304) {
        int j = i - 65536;
        int n = j >> 8, k = j & 255;
        W1t[j] = (_Float16)W1[k * 128 + n];
    } else if (i < 98304 + 2560) {
        int j = i - 98304;               // j = kk*40 + lane
        int kk = j / 40, lane = j - kk * 40;
        f16x2 p = { (_Float16)lw[(2 * kk) * 40 + lane],
                    (_Float16)lw[(2 * kk + 1) * 40 + lane] };
        lwp[j] = p;
    } else if (i < 98304 + 2560 + 256) {
        gcur[i - 98304 - 2560] = 0;
    }
}

// ---------------------------------------------------------------------------
// pass1_direct: bin packed (lrow|dst) into PADDED per-bucket slots.
// Per-block LDS histogram -> one gcur atomic per bucket -> append.
// ---------------------------------------------------------------------------
__global__ __launch_bounds__(256) void pass1_direct_kernel(const int* __restrict__ src,
                                                           const int* __restrict__ dst,
                                                           int* __restrict__ gcur,
                                                           int* __restrict__ pairs, int E)
{
    __shared__ int hist[256];
    __shared__ int cur[256];
    int t = threadIdx.x;
    hist[t] = 0;
    __syncthreads();
    int base = blockIdx.x * 4096;
    int s_[16], d_[16];
#pragma unroll
    for (int j = 0; j < 16; ++j) {
        int i = base + j * 256 + t;
        if (i < E) {
            s_[j] = src[i];
            d_[j] = dst[i];
            atomicAdd(&hist[s_[j] >> BIN_SHIFT], 1);
        } else s_[j] = -1;
    }
    __syncthreads();
    cur[t] = atomicAdd(&gcur[t], hist[t]);   // within-bucket reservation
    __syncthreads();
#pragma unroll
    for (int j = 0; j < 16; ++j) {
        if (s_[j] >= 0) {
            int b = s_[j] >> BIN_SHIFT;
            int pos = atomicAdd(&cur[b], 1);
            pairs[b * BUCKET_CAP + pos] = ((s_[j] & (BIN_ROWS - 1)) << DST_BITS) | d_[j];
        }
    }
}

// ---------------------------------------------------------------------------
// csr_kernel: one block per bucket.  Derives bucket edge-base via in-LDS scan
// of gcur, counts rows, scans 512 rows -> rowptr, then scatters csr_dst.
// ---------------------------------------------------------------------------
__global__ __launch_bounds__(256) void csr_kernel(const int* __restrict__ pairs,
                                                  const int* __restrict__ gcur,
                                                  int* __restrict__ rowptr,
                                                  int* __restrict__ csr_dst,
                                                  int N, int E)
{
    __shared__ int scan[256];
    __shared__ int c[BIN_ROWS];
    __shared__ int tsum[256];
    int b = blockIdx.x, t = threadIdx.x;
    int rowbase = b << BIN_SHIFT;
    int nrows = min(BIN_ROWS, N - rowbase);

    // bucket edge counts -> inclusive scan -> this bucket's base/count
    int v = gcur[t];
    scan[t] = v;
    __syncthreads();
    for (int off = 1; off < 256; off <<= 1) {
        int u = (t >= off) ? scan[t - off] : 0;
        __syncthreads();
        scan[t] += u;
        __syncthreads();
    }
    int ebase = (b > 0) ? scan[b - 1] : 0;
    int myCount = scan[b] - ebase;

    // per-row counts
    c[t] = 0; c[t + 256] = 0;
    __syncthreads();
    const int* bp = pairs + (size_t)b * BUCKET_CAP;
    for (int i = t; i < myCount; i += 256)
        atomicAdd(&c[bp[i] >> DST_BITS], 1);
    __syncthreads();

    // scan 512 rows (2 per thread) -> rowptr + cursors
    int c0 = c[2 * t], c1 = c[2 * t + 1];
    int s = c0 + c1;
    tsum[t] = s;
    __syncthreads();
    for (int off = 1; off < 256; off <<= 1) {
        int u = (t >= off) ? tsum[t - off] : 0;
        __syncthreads();
        tsum[t] += u;
        __syncthreads();
    }
    int excl = ebase + tsum[t] - s;
    if (2 * t < nrows)     rowptr[rowbase + 2 * t] = excl;
    if (2 * t + 1 < nrows) rowptr[rowbase + 2 * t + 1] = excl + c0;
    if (b == (int)gridDim.x - 1 && t == 0) rowptr[N] = E;
    // cursors reuse c[] (each thread rewrites the two slots it owns)
    c[2 * t] = excl;
    c[2 * t + 1] = excl + c0;
    __syncthreads();

    // scatter
    for (int i = t; i < myCount; i += 256) {
        int p = bp[i];
        int pos = atomicAdd(&c[p >> DST_BITS], 1);
        csr_dst[pos] = p & DST_MASK;
    }
}

// ---------------------------------------------------------------------------
// MFMA f16 GEMM v3: one block-column covers ALL Nw columns (GBN = Nw), A
// streamed once.  Double-buffered LDS, global loads issued before MFMA,
// ONE barrier per k-step.  FUSE_S: per-wave partial row-dots reduced across
// waves via LDS, then plain stores.
// ---------------------------------------------------------------------------
#define GBM 64
#define GBK 32
#define LDP 40

template <bool CVTA, bool FUSE_S, int GBN>
__global__ __launch_bounds__(256) void gemm16_kernel(const void* __restrict__ Ap,
                                                     const _Float16* __restrict__ Bt,
                                                     _Float16* __restrict__ C,
                                                     int M, int K,
                                                     const float* __restrict__ avec,
                                                     int aoff,
                                                     float* __restrict__ ssrc,
                                                     float* __restrict__ sdst)
{
    constexpr int NT = GBN / 64;          // n-frags per wave; also B vecs per thread
    __shared__ __align__(16) _Float16 Ash[2][GBM * LDP];
    __shared__ __align__(16) _Float16 Bsh[2][GBN * LDP];
    __shared__ float2 spart[4][GBM];      // per-wave partial (ps,pd) per local row
    const int tid = threadIdx.x;
    const int lane = tid & 63;
    const int w = tid >> 6;               // 0..3
    const int m0 = blockIdx.x * GBM;
    const int l15 = lane & 15;
    const int kq = lane >> 4;
    const int sr = tid >> 2;              // 0..63
    const int sc = tid & 3;
    const int wc = w * (GBN / 4);         // wave col base
    const int gmS = m0 + sr;

    f16x8 va, vb[NT];
    auto loadT = [&](int k0, f16x8& a, f16x8* b) {
        a = f16x8{};
        if (gmS < M) {
            if constexpr (CVTA) {
                const float* Af = (const float*)Ap;
                float4 u0 = *(const float4*)(Af + (size_t)gmS * K + k0 + sc * 8);
                float4 u1 = *(const float4*)(Af + (size_t)gmS * K + k0 + sc * 8 + 4);
                a[0] = (_Float16)u0.x; a[1] = (_Float16)u0.y;
                a[2] = (_Float16)u0.z; a[3] = (_Float16)u0.w;
                a[4] = (_Float16)u1.x; a[5] = (_Float16)u1.y;
                a[6] = (_Float16)u1.z; a[7] = (_Float16)u1.w;
            } else {
                a = *(const f16x8*)((const _Float16*)Ap + (size_t)gmS * K + k0 + sc * 8);
            }
        }
#pragma unroll
        for (int it = 0; it < NT; ++it)
            b[it] = *(const f16x8*)(Bt + (size_t)(sr + it * 64) * K + k0 + sc * 8);
    };
    auto storeT = [&](int buf, const f16x8& a, const f16x8* b) {
        *(f16x8*)&Ash[buf][sr * LDP + sc * 8] = a;
#pragma unroll
        for (int it = 0; it < NT; ++it)
            *(f16x8*)&Bsh[buf][(sr + it * 64) * LDP + sc * 8] = b[it];
    };

    loadT(0, va, vb);
    storeT(0, va, vb);
    __syncthreads();

    f32x4 acc[4][NT] = {};
    int cur = 0;
    for (int k0 = 0; k0 < K; k0 += GBK) {
        bool nxt = (k0 + GBK) < K;
        f16x8 na, nb[NT];
        if (nxt) loadT(k0 + GBK, na, nb);     // issue early; hides under MFMA

        f16x8 af[4], bf[NT];
#pragma unroll
        for (int mt = 0; mt < 4; ++mt)
            af[mt] = *(const f16x8*)&Ash[cur][(mt * 16 + l15) * LDP + kq * 8];
#pragma unroll
        for (int nt = 0; nt < NT; ++nt)
            bf[nt] = *(const f16x8*)&Bsh[cur][(wc + nt * 16 + l15) * LDP + kq * 8];
#pragma unroll
        for (int mt = 0; mt < 4; ++mt)
#pragma unroll
            for (int nt = 0; nt < NT; ++nt)
                acc[mt][nt] = __builtin_amdgcn_mfma_f32_16x16x32_f16(af[mt], bf[nt],
                                                                     acc[mt][nt], 0, 0, 0);
        if (nxt) storeT(cur ^ 1, na, nb);
        __syncthreads();
        cur ^= 1;
    }

#pragma unroll
    for (int mt = 0; mt < 4; ++mt) {
#pragma unroll
        for (int r = 0; r < 4; ++r) {
            int gm = m0 + mt * 16 + kq * 4 + r;
            if (gm < M) {
#pragma unroll
                for (int nt = 0; nt < NT; ++nt)
                    C[(size_t)gm * GBN + wc + nt * 16 + l15] = (_Float16)acc[mt][nt][r];
            }
        }
    }

    if constexpr (FUSE_S) {
        float as[NT], ad[NT];
#pragma unroll
        for (int nt = 0; nt < NT; ++nt) {
            int c = wc + nt * 16 + l15;
            as[nt] = avec[c];
            ad[nt] = avec[aoff + c];
        }
#pragma unroll
        for (int mt = 0; mt < 4; ++mt) {
#pragma unroll
            for (int r = 0; r < 4; ++r) {
                float ps = 0.f, pd = 0.f;
#pragma unroll
                for (int nt = 0; nt < NT; ++nt) {
                    float v = acc[mt][nt][r];
                    ps += v * as[nt];
                    pd += v * ad[nt];
                }
#pragma unroll
                for (int off = 1; off < 16; off <<= 1) {
                    ps += __shfl_xor(ps, off);
                    pd += __shfl_xor(pd, off);
                }
                int lr = mt * 16 + kq * 4 + r;       // local row 0..63
                if (l15 == 0) spart[w][lr] = make_float2(ps, pd);
            }
        }
        __syncthreads();
        if (tid < GBM) {
            float2 p0 = spart[0][tid], p1 = spart[1][tid];
            float2 p2 = spart[2][tid], p3 = spart[3][tid];
            int gm = m0 + tid;
            if (gm < M) {
                ssrc[gm] = p0.x + p1.x + p2.x + p3.x;
                sdst[gm] = p0.y + p1.y + p2.y + p3.y;
            }
        }
    }
}

// ---------------------------------------------------------------------------
// FUSED per-row softmax + aggregation + ELU (+ optional final linear +
// log_softmax via v_dot2_f32_f16 for the last layer).
// One wave per row; 16 lanes/edge; 4-edge-deep gather pipeline; packed f16
// FMA accumulate.  deg<=128: weights+dst in per-wave LDS.  deg>128: spill.
// ---------------------------------------------------------------------------
__device__ __forceinline__ float eluf(float x) { return x > 0.f ? x : expm1f(x); }

union h2u { f16x2 h; unsigned u; };
__device__ __forceinline__ unsigned pkadd(unsigned a, unsigned b)
{
    h2u x, y; x.u = a; y.u = b; x.h += y.h; return x.u;
}

template <int D, bool FUSE_FINAL>
__global__ __launch_bounds__(256) void attnagg_kernel(const _Float16* __restrict__ h,
                                                      const float* __restrict__ ssrc,
                                                      const float* __restrict__ sdst,
                                                      const int* __restrict__ csr_dst,
                                                      const int* __restrict__ rowptr,
                                                      float* __restrict__ attn_spill,
                                                      _Float16* __restrict__ out16,
                                                      const f16x2* __restrict__ lwp,
                                                      const float* __restrict__ lb,
                                                      float* __restrict__ outf, int nrows)
{
    constexpr int HPL = D / 16;            // halves per lane: 16 (D=256) or 8 (D=128)
    constexpr int NV = HPL / 8;            // f16x8 vectors per lane: 2 or 1
    __shared__ float2 wdbuf[4][128];
    __shared__ __align__(16) _Float16 rowbuf[FUSE_FINAL ? 4 : 1][128];
    int lane = threadIdx.x & 63;
    int wv = threadIdx.x >> 6;
    int row = blockIdx.x * 4 + wv;
    if (row >= nrows) return;
    int beg = rowptr[row], end = rowptr[row + 1];
    int deg = end - beg;
    bool small = (deg <= 128);

    if (deg > 0) {
        float ss = ssrc[row];
        if (small) {
            int e0 = beg + lane, e1 = e0 + 64;
            int d0 = 0, d1 = 0;
            float sc0 = -INFINITY, sc1 = -INFINITY;
            if (e0 < end) {
                d0 = csr_dst[e0];
                float sc = ss + sdst[d0];
                sc0 = (sc > 0.f) ? sc : LRELU_ALPHA * sc;
            }
            if (e1 < end) {
                d1 = csr_dst[e1];
                float sc = ss + sdst[d1];
                sc1 = (sc > 0.f) ? sc : LRELU_ALPHA * sc;
            }
            float m = fmaxf(sc0, sc1);
#pragma unroll
            for (int off = 32; off; off >>= 1) m = fmaxf(m, __shfl_xor(m, off));
            float ex0 = (e0 < end) ? expf(sc0 - m) : 0.f;
            float ex1 = (e1 < end) ? expf(sc1 - m) : 0.f;
            float z = ex0 + ex1;
#pragma unroll
            for (int off = 32; off; off >>= 1) z += __shfl_xor(z, off);
            float rz = 1.f / z;
            if (e0 < end) wdbuf[wv][lane] = make_float2(ex0 * rz, __int_as_float(d0));
            if (e1 < end) wdbuf[wv][64 + lane] = make_float2(ex1 * rz, __int_as_float(d1));
        } else {
            float m = -INFINITY;
            for (int e = beg + lane; e < end; e += 64) {
                float sc = ss + sdst[csr_dst[e]];
                sc = (sc > 0.f) ? sc : LRELU_ALPHA * sc;
                attn_spill[e] = sc;
                m = fmaxf(m, sc);
            }
#pragma unroll
            for (int off = 32; off; off >>= 1) m = fmaxf(m, __shfl_xor(m, off));
            float z = 0.f;
            for (int e = beg + lane; e < end; e += 64) {
                float ex = expf(attn_spill[e] - m);
                attn_spill[e] = ex;
                z += ex;
            }
#pragma unroll
            for (int off = 32; off; off >>= 1) z += __shfl_xor(z, off);
            float rz = 1.f / z;
            for (int e = beg + lane; e < end; e += 64) attn_spill[e] *= rz;
        }
    }

    // ---- aggregation: 16 lanes/edge, 4-edge-deep pipeline ----
    int sub = lane >> 4;          // 0..3
    int cl = lane & 15;
    const _Float16* hbase = h + cl * HPL;
    f16x8 acc[NV] = {};

    if (small) {
        int k = sub;
        for (; k + 12 < deg; k += 16) {
            float2 wd0 = wdbuf[wv][k];
            float2 wd1 = wdbuf[wv][k + 4];
            float2 wd2 = wdbuf[wv][k + 8];
            float2 wd3 = wdbuf[wv][k + 12];
            const _Float16* p0 = hbase + ((unsigned)__float_as_int(wd0.y) * D);
            const _Float16* p1 = hbase + ((unsigned)__float_as_int(wd1.y) * D);
            const _Float16* p2 = hbase + ((unsigned)__float_as_int(wd2.y) * D);
            const _Float16* p3 = hbase + ((unsigned)__float_as_int(wd3.y) * D);
            f16x8 v0[NV], v1[NV], v2[NV], v3[NV];
#pragma unroll
            for (int q = 0; q < NV; ++q) v0[q] = *(const f16x8*)(p0 + q * 8);
#pragma unroll
            for (int q = 0; q < NV; ++q) v1[q] = *(const f16x8*)(p1 + q * 8);
#pragma unroll
            for (int q = 0; q < NV; ++q) v2[q] = *(const f16x8*)(p2 + q * 8);
#pragma unroll
            for (int q = 0; q < NV; ++q) v3[q] = *(const f16x8*)(p3 + q * 8);
            _Float16 w0 = (_Float16)wd0.x, w1 = (_Float16)wd1.x;
            _Float16 w2 = (_Float16)wd2.x, w3 = (_Float16)wd3.x;
            f16x8 a0 = {w0, w0, w0, w0, w0, w0, w0, w0};
            f16x8 a1 = {w1, w1, w1, w1, w1, w1, w1, w1};
            f16x8 a2 = {w2, w2, w2, w2, w2, w2, w2, w2};
            f16x8 a3 = {w3, w3, w3, w3, w3, w3, w3, w3};
#pragma unroll
            for (int q = 0; q < NV; ++q) acc[q] += v0[q] * a0;
#pragma unroll
            for (int q = 0; q < NV; ++q) acc[q] += v1[q] * a1;
#pragma unroll
            for (int q = 0; q < NV; ++q) acc[q] += v2[q] * a2;
#pragma unroll
            for (int q = 0; q < NV; ++q) acc[q] += v3[q] * a3;
        }
        for (; k < deg; k += 4) {
            float2 wd = wdbuf[wv][k];
            const _Float16* hp = hbase + ((unsigned)__float_as_int(wd.y) * D);
            f16x8 vv[NV];
#pragma unroll
            for (int q = 0; q < NV; ++q) vv[q] = *(const f16x8*)(hp + q * 8);
            _Float16 wh = (_Float16)wd.x;
            f16x8 a8 = {wh, wh, wh, wh, wh, wh, wh, wh};
#pragma unroll
            for (int q = 0; q < NV; ++q) acc[q] += vv[q] * a8;
        }
    } else {
        for (int k = sub; k < deg; k += 4) {
            float a = attn_spill[beg + k];
            int d = csr_dst[beg + k];
            const _Float16* hp = hbase + ((unsigned)d * D);
            f16x8 vv[NV];
#pragma unroll
            for (int q = 0; q < NV; ++q) vv[q] = *(const f16x8*)(hp + q * 8);
            _Float16 wh = (_Float16)a;
            f16x8 a8 = {wh, wh, wh, wh, wh, wh, wh, wh};
#pragma unroll
            for (int q = 0; q < NV; ++q) acc[q] += vv[q] * a8;
        }
    }

    // packed reduce across the 4 sub-groups
    union { f16x8 v; unsigned w[4]; } A[NV];
#pragma unroll
    for (int q = 0; q < NV; ++q) A[q].v = acc[q];
#pragma unroll
    for (int q = 0; q < NV; ++q)
#pragma unroll
        for (int i = 0; i < 4; ++i) {
            unsigned u = A[q].w[i];
            u = pkadd(u, (unsigned)__shfl_xor((int)u, 16));
            u = pkadd(u, (unsigned)__shfl_xor((int)u, 32));
            A[q].w[i] = u;
        }

    if constexpr (!FUSE_FINAL) {
        if (sub == 0) {
            _Float16* op = out16 + (size_t)row * D + cl * HPL;
#pragma unroll
            for (int q = 0; q < NV; ++q) {
                f16x8 o;
#pragma unroll
                for (int j = 0; j < 8; ++j) o[j] = (_Float16)eluf((float)A[q].v[j]);
                *(f16x8*)(op + q * 8) = o;
            }
        }
    } else {
        // D == 128: ELU row -> per-wave LDS (f16), then logits via dot2
        if (sub == 0) {
            f16x8 o;
#pragma unroll
            for (int j = 0; j < 8; ++j) o[j] = (_Float16)eluf((float)A[0].v[j]);
            *(f16x8*)&rowbuf[wv][cl * 8] = o;
        }
        __builtin_amdgcn_wave_barrier();   // sched fence; in-order DS pipe per wave
        float logit = 0.f;
        if (lane < 40) {
            float s = lb[lane];
            const f16x2* rp = (const f16x2*)&rowbuf[wv][0];
#pragma unroll 8
            for (int kk = 0; kk < 64; ++kk)
                s = __builtin_amdgcn_fdot2(rp[kk], lwp[kk * 40 + lane], s, false);
            logit = s;
        }
        float v = (lane < 40) ? logit : -INFINITY;
#pragma unroll
        for (int off = 32; off; off >>= 1) v = fmaxf(v, __shfl_xor(v, off));
        float ex = (lane < 40) ? expf(logit - v) : 0.f;
        float zs = ex;
#pragma unroll
        for (int off = 32; off; off >>= 1) zs += __shfl_xor(zs, off);
        if (lane < 40) outf[(size_t)row * 40 + lane] = logit - v - logf(zs);
    }
}

// ---------------------------------------------------------------------------
extern "C" void kernel_launch(void* const* d_in, const int* in_sizes, int n_in,
                              void* d_out, int out_size, void* d_ws, size_t ws_size,
                              hipStream_t stream)
{
    const float* x   = (const float*)d_in[0];   // [N,256]
    const int*  edge = (const int*)d_in[1];     // [2,E]
    const float* W0  = (const float*)d_in[2];   // [256,256]
    const float* a0  = (const float*)d_in[3];   // [512,1]
    const float* W1  = (const float*)d_in[4];   // [256,128]
    const float* a1  = (const float*)d_in[5];   // [256,1]
    const float* lw  = (const float*)d_in[6];   // [128,40]
    const float* lb  = (const float*)d_in[7];   // [40]
    float* out = (float*)d_out;

    const int N = in_sizes[0] / 256;
    const int E = in_sizes[1] / 2;
    const int* src = edge;
    const int* dst = edge + E;

    // ---- workspace layout ----
    _Float16* bufA = (_Float16*)d_ws;                 // N*256 halves (h0, then h1)
    _Float16* bufB = bufA + (size_t)N * 256;          // N*256 halves (h0')
    _Float16* W0t  = bufB + (size_t)N * 256;          // 256*256
    _Float16* W1t  = W0t + 256 * 256;                 // 128*256
    f16x2*    lwp  = (f16x2*)(W1t + 128 * 256);       // 2560 f16x2
    float* ssrc = (float*)(lwp + 2560);                // N
    float* sdst = ssrc + N;                            // N
    float* attn = sdst + N;                            // E (spill for deg>128 rows)
    int* rowptr  = (int*)(attn + E);                   // N+1
    int* csr_dst = rowptr + (N + 1);                   // E
    int* gcur    = csr_dst + E;                        // 256
    // pairs aliases bufA+bufB: dead before gemm-0 writes bufA (stream-ordered)
    int* pairs   = (int*)bufA;                         // 256*BUCKET_CAP ints (~18.9MB)

    const int rowBlocks = (N + 3) / 4;
    const int NB = (N + BIN_ROWS - 1) >> BIN_SHIFT;    // buckets (<=256)
    const int blocksE = (E + 4095) / 4096;
    const int gemmBlocks = (N + GBM - 1) / GBM;

    // ---- prep (transposes + lw pack + gcur zero) ----
    prep_kernel<<<396, 256, 0, stream>>>(W0, W1, lw, W0t, W1t, lwp, gcur);

    // ---- CSR build: direct padded binning + fused rowptr/scatter ----
    pass1_direct_kernel<<<blocksE, 256, 0, stream>>>(src, dst, gcur, pairs, E);
    csr_kernel<<<NB, 256, 0, stream>>>(pairs, gcur, rowptr, csr_dst, N, E);

    // ---- layer 0: d = 256 ----
    gemm16_kernel<true, true, 256><<<gemmBlocks, 256, 0, stream>>>(
        x, W0t, bufA, N, 256, a0, 256, ssrc, sdst);
    attnagg_kernel<256, false><<<rowBlocks, 256, 0, stream>>>(
        bufA, ssrc, sdst, csr_dst, rowptr, attn, bufB, nullptr, nullptr, nullptr, N);

    // ---- layer 1: d = 128 (final linear + log_softmax fused) ----
    gemm16_kernel<false, true, 128><<<gemmBlocks, 256, 0, stream>>>(
        bufB, W1t, bufA, N, 256, a1, 128, ssrc, sdst);
    attnagg_kernel<128, true><<<rowBlocks, 256, 0, stream>>>(
        bufA, ssrc, sdst, csr_dst, rowptr, attn, nullptr, lwp, lb, out, N);
}